// Round 2
// baseline (321.593 us; speedup 1.0000x reference)
//
#include <hip/hip_runtime.h>
#include <math.h>

#define NB 8
#define NN 4096
#define NDIM 512
#define NH 8
#define NDH 64
#define QKVC 1536
#define NROWS (NB * NN)
#define EPSF 1e-5f
#define INV_N (1.0f / 4096.0f)
// log2(10000)/16
#define L2_10K_16 0.8304820237218406f

typedef __bf16 bf16x8_t __attribute__((ext_vector_type(8)));
typedef float f32x4_t __attribute__((ext_vector_type(4)));
typedef unsigned short u16x8 __attribute__((ext_vector_type(8)));

__device__ inline unsigned short f2bf(float f) {
    unsigned u = __builtin_bit_cast(unsigned, f);
    u += 0x7fff + ((u >> 16) & 1);          // round-to-nearest-even
    return (unsigned short)(u >> 16);
}
__device__ inline float bf2f(unsigned short u) {
    unsigned v = (unsigned)u << 16;
    return __builtin_bit_cast(float, v);
}

// async global->LDS, 16B per lane; LDS dest = wave-uniform base + lane*16
#define GLOAD_LDS16(g, s) __builtin_amdgcn_global_load_lds(                    \
    (const __attribute__((address_space(1))) void*)(g),                        \
    (__attribute__((address_space(3))) void*)(s), 16, 0, 0)

// ---------------------------------------------------------------------------
// fp32 -> bf16 convert, 8 elems/thread. n must be multiple of 8.
// ---------------------------------------------------------------------------
__global__ __launch_bounds__(256)
void cvt_bf16_kernel(const float* __restrict__ s, unsigned short* __restrict__ d, int n)
{
    const int i = (blockIdx.x * 256 + threadIdx.x) * 8;
    if (i >= n) return;
    float4 a = *(const float4*)(s + i);
    float4 b = *(const float4*)(s + i + 4);
    ushort4 lo, hi;
    lo.x = f2bf(a.x); lo.y = f2bf(a.y); lo.z = f2bf(a.z); lo.w = f2bf(a.w);
    hi.x = f2bf(b.x); hi.y = f2bf(b.y); hi.z = f2bf(b.z); hi.w = f2bf(b.w);
    *(ushort4*)(d + i)     = lo;
    *(ushort4*)(d + i + 4) = hi;
}

// fp32 -> bf16 with scale (for dots -> dots_bf * 1/N), 4 elems/thread
__global__ __launch_bounds__(256)
void cvt_dots_kernel(const float* __restrict__ s, unsigned short* __restrict__ d)
{
    const int i = (blockIdx.x * 256 + threadIdx.x) * 4;
    float4 a = *(const float4*)(s + i);
    ushort4 o;
    o.x = f2bf(a.x * INV_N); o.y = f2bf(a.y * INV_N);
    o.z = f2bf(a.z * INV_N); o.w = f2bf(a.w * INV_N);
    *(ushort4*)(d + i) = o;
}

// ---------------------------------------------------------------------------
// Fused QKV GEMM, 256x256 tile, BK=64, 8 waves (2M x 4N), per-wave C 128x64.
// m201-style 4-phase/K-tile schedule: per phase {vmcnt(4); barrier; ds_read
// register subtile; stage 1 half-tile of tile t+1; setprio; 16 MFMA}.
// 2-deep LDS dbuf (128 KB). Stage order per tile [A0,B0,B1,A1]; consume
// order ph0:{A0,B0} ph1:{B1} ph2:{A1} ph3:{} -> vmcnt(4) (= all but newest
// 2 half-tiles complete) guarantees each phase's data has landed.
// Half-tile A h = rows with (r>>6)&1==h packed contiguously (local
// l = ((r>>7)<<6)|(r&63)); B h = rows with (r>>5)&1==h (l=((r>>6)<<5)|(r&31))
// so each wave's quadrant reads touch exactly one half-tile.
// XOR swizzle: LDS chunk (16B) ch holds global chunk ch^(l&7); applied on
// the global SOURCE address (gload_lds dest must stay linear, rule 21).
// Epilogue: RoPE(q,k) + LN(k,v), bf16 out (wave owns one head's 64 cols).
// ---------------------------------------------------------------------------
__global__ __launch_bounds__(512, 2)
void gemm_qkv_fused(const unsigned short* __restrict__ A,
                    const unsigned short* __restrict__ Bm,
                    const float* __restrict__ pos,
                    const float* __restrict__ gk, const float* __restrict__ bk,
                    const float* __restrict__ gv, const float* __restrict__ bvv,
                    unsigned short* __restrict__ qkvb)
{
    // per buffer: A 2x[128][64] (32KB) then B 2x[128][64] (32KB); x2 = 128KB
    __shared__ __align__(16) unsigned short lds[2 * 32768];

    const int tid  = threadIdx.x;
    const int wave = tid >> 6;
    const int lane = tid & 63;

    // T1: bijective XCD swizzle (nwg = 768, 768 % 8 == 0)
    int flat = blockIdx.y * 6 + blockIdx.x;
    flat = (flat & 7) * 96 + (flat >> 3);
    const int bx = flat % 6;
    const int by = flat / 6;
    const int m0 = by * 256;
    const int n0 = bx * 256;

    const int warp_m = wave >> 2;       // 0..1 -> rows warp_m*128
    const int warp_n = wave & 3;        // 0..3 -> cols warp_n*64 (one head)
    const int fr = lane & 15;
    const int fq = lane >> 4;           // 0..3
    const int ch0 = ((fq ^ (fr & 7)) << 3);   // shorts; ks=0 chunk offset
    const int ch1 = ch0 ^ 32;                 // ks=1

    // stage source addressing (pre-swizzled global chunk, rule 21)
    const int r6 = tid >> 3;                  // 0..63 (row within 64-row call)
    const int cs = (((tid & 7) ^ (r6 & 7)) << 3);
    const unsigned short* Asrc = A  + (size_t)(m0 + r6) * NDIM + cs;
    const unsigned short* Bsrc = Bm + (size_t)(n0 + (r6 >> 5) * 64 + (r6 & 31)) * NDIM + cs;
    const int sdst = wave * 512;              // per-wave linear LDS dest (shorts)

#define STG_A(tt, h, c) GLOAD_LDS16(Asrc + (size_t)((c) * 128 + (h) * 64) * NDIM + (tt) * 64, \
        &lds[(((tt) & 1) << 15) + ((h) << 13) + ((c) << 12) + sdst])
#define STG_B(tt, h, c) GLOAD_LDS16(Bsrc + (size_t)((c) * 128 + (h) * 32) * NDIM + (tt) * 64, \
        &lds[(((tt) & 1) << 15) + 16384 + ((h) << 13) + ((c) << 12) + sdst])
#define VMCNT4 asm volatile("s_waitcnt vmcnt(4)" ::: "memory")
#define BARF   { __builtin_amdgcn_s_barrier(); asm volatile("" ::: "memory"); }

    f32x4_t acc[8][4] = {};

    // prologue: stage tile 0 in order A0,B0,B1,A1 (8 gloads)
    STG_A(0, 0, 0); STG_A(0, 0, 1);
    STG_B(0, 0, 0); STG_B(0, 0, 1);
    STG_B(0, 1, 0); STG_B(0, 1, 1);
    STG_A(0, 1, 0); STG_A(0, 1, 1);

    const unsigned short* Afr = &lds[(warp_m * 64 + fr) * 64];          // +rb +mh*8192 +mi*1024 +ch
    const unsigned short* Bfr = &lds[16384 + (warp_n * 32 + fr) * 64];  // +rb +nh*8192 +nj*1024 +ch

    bf16x8_t a0[4][2], a1[4][2], b0[2][2], b1[2][2];

    for (int tt = 0; tt < 7; ++tt) {
        const int rb = (tt & 1) << 15;
        // ---- phase 0: read A0,B0; stage A0(t+1); MFMA (m0..3 x n0..1) ----
        VMCNT4; BARF;
        #pragma unroll
        for (int mi = 0; mi < 4; ++mi) {
            a0[mi][0] = *(const bf16x8_t*)&Afr[rb + mi * 1024 + ch0];
            a0[mi][1] = *(const bf16x8_t*)&Afr[rb + mi * 1024 + ch1];
        }
        #pragma unroll
        for (int nj = 0; nj < 2; ++nj) {
            b0[nj][0] = *(const bf16x8_t*)&Bfr[rb + nj * 1024 + ch0];
            b0[nj][1] = *(const bf16x8_t*)&Bfr[rb + nj * 1024 + ch1];
        }
        STG_A(tt + 1, 0, 0); STG_A(tt + 1, 0, 1);
        __builtin_amdgcn_s_setprio(1);
        #pragma unroll
        for (int mi = 0; mi < 4; ++mi)
            #pragma unroll
            for (int nj = 0; nj < 2; ++nj) {
                acc[mi][nj] = __builtin_amdgcn_mfma_f32_16x16x32_bf16(a0[mi][0], b0[nj][0], acc[mi][nj], 0, 0, 0);
                acc[mi][nj] = __builtin_amdgcn_mfma_f32_16x16x32_bf16(a0[mi][1], b0[nj][1], acc[mi][nj], 0, 0, 0);
            }
        __builtin_amdgcn_s_setprio(0);
        // ---- phase 1: read B1; stage B0(t+1); MFMA (m0..3 x n2..3) ----
        VMCNT4; BARF;
        #pragma unroll
        for (int nj = 0; nj < 2; ++nj) {
            b1[nj][0] = *(const bf16x8_t*)&Bfr[rb + 8192 + nj * 1024 + ch0];
            b1[nj][1] = *(const bf16x8_t*)&Bfr[rb + 8192 + nj * 1024 + ch1];
        }
        STG_B(tt + 1, 0, 0); STG_B(tt + 1, 0, 1);
        __builtin_amdgcn_s_setprio(1);
        #pragma unroll
        for (int mi = 0; mi < 4; ++mi)
            #pragma unroll
            for (int nj = 0; nj < 2; ++nj) {
                acc[mi][2 + nj] = __builtin_amdgcn_mfma_f32_16x16x32_bf16(a0[mi][0], b1[nj][0], acc[mi][2 + nj], 0, 0, 0);
                acc[mi][2 + nj] = __builtin_amdgcn_mfma_f32_16x16x32_bf16(a0[mi][1], b1[nj][1], acc[mi][2 + nj], 0, 0, 0);
            }
        __builtin_amdgcn_s_setprio(0);
        // ---- phase 2: read A1; stage B1(t+1); MFMA (m4..7 x n0..1) ----
        VMCNT4; BARF;
        #pragma unroll
        for (int mi = 0; mi < 4; ++mi) {
            a1[mi][0] = *(const bf16x8_t*)&Afr[rb + 8192 + mi * 1024 + ch0];
            a1[mi][1] = *(const bf16x8_t*)&Afr[rb + 8192 + mi * 1024 + ch1];
        }
        STG_B(tt + 1, 1, 0); STG_B(tt + 1, 1, 1);
        __builtin_amdgcn_s_setprio(1);
        #pragma unroll
        for (int mi = 0; mi < 4; ++mi)
            #pragma unroll
            for (int nj = 0; nj < 2; ++nj) {
                acc[4 + mi][nj] = __builtin_amdgcn_mfma_f32_16x16x32_bf16(a1[mi][0], b0[nj][0], acc[4 + mi][nj], 0, 0, 0);
                acc[4 + mi][nj] = __builtin_amdgcn_mfma_f32_16x16x32_bf16(a1[mi][1], b0[nj][1], acc[4 + mi][nj], 0, 0, 0);
            }
        __builtin_amdgcn_s_setprio(0);
        // ---- phase 3: stage A1(t+1); MFMA (m4..7 x n2..3) (regs only) ----
        STG_A(tt + 1, 1, 0); STG_A(tt + 1, 1, 1);
        __builtin_amdgcn_s_setprio(1);
        #pragma unroll
        for (int mi = 0; mi < 4; ++mi)
            #pragma unroll
            for (int nj = 0; nj < 2; ++nj) {
                acc[4 + mi][2 + nj] = __builtin_amdgcn_mfma_f32_16x16x32_bf16(a1[mi][0], b1[nj][0], acc[4 + mi][2 + nj], 0, 0, 0);
                acc[4 + mi][2 + nj] = __builtin_amdgcn_mfma_f32_16x16x32_bf16(a1[mi][1], b1[nj][1], acc[4 + mi][2 + nj], 0, 0, 0);
            }
        __builtin_amdgcn_s_setprio(0);
    }
    // ---- final K-tile (tt=7, buffer 1): drain once, no stages/barriers ----
    {
        const int rb = 32768;
        asm volatile("s_waitcnt vmcnt(0)" ::: "memory");
        BARF;
        #pragma unroll
        for (int mi = 0; mi < 4; ++mi) {
            a0[mi][0] = *(const bf16x8_t*)&Afr[rb + mi * 1024 + ch0];
            a0[mi][1] = *(const bf16x8_t*)&Afr[rb + mi * 1024 + ch1];
        }
        #pragma unroll
        for (int nj = 0; nj < 2; ++nj) {
            b0[nj][0] = *(const bf16x8_t*)&Bfr[rb + nj * 1024 + ch0];
            b0[nj][1] = *(const bf16x8_t*)&Bfr[rb + nj * 1024 + ch1];
        }
        #pragma unroll
        for (int mi = 0; mi < 4; ++mi)
            #pragma unroll
            for (int nj = 0; nj < 2; ++nj) {
                acc[mi][nj] = __builtin_amdgcn_mfma_f32_16x16x32_bf16(a0[mi][0], b0[nj][0], acc[mi][nj], 0, 0, 0);
                acc[mi][nj] = __builtin_amdgcn_mfma_f32_16x16x32_bf16(a0[mi][1], b0[nj][1], acc[mi][nj], 0, 0, 0);
            }
        #pragma unroll
        for (int nj = 0; nj < 2; ++nj) {
            b1[nj][0] = *(const bf16x8_t*)&Bfr[rb + 8192 + nj * 1024 + ch0];
            b1[nj][1] = *(const bf16x8_t*)&Bfr[rb + 8192 + nj * 1024 + ch1];
        }
        #pragma unroll
        for (int mi = 0; mi < 4; ++mi)
            #pragma unroll
            for (int nj = 0; nj < 2; ++nj) {
                acc[mi][2 + nj] = __builtin_amdgcn_mfma_f32_16x16x32_bf16(a0[mi][0], b1[nj][0], acc[mi][2 + nj], 0, 0, 0);
                acc[mi][2 + nj] = __builtin_amdgcn_mfma_f32_16x16x32_bf16(a0[mi][1], b1[nj][1], acc[mi][2 + nj], 0, 0, 0);
            }
        #pragma unroll
        for (int mi = 0; mi < 4; ++mi) {
            a1[mi][0] = *(const bf16x8_t*)&Afr[rb + 8192 + mi * 1024 + ch0];
            a1[mi][1] = *(const bf16x8_t*)&Afr[rb + 8192 + mi * 1024 + ch1];
        }
        #pragma unroll
        for (int mi = 0; mi < 4; ++mi)
            #pragma unroll
            for (int nj = 0; nj < 2; ++nj) {
                acc[4 + mi][nj] = __builtin_amdgcn_mfma_f32_16x16x32_bf16(a1[mi][0], b0[nj][0], acc[4 + mi][nj], 0, 0, 0);
                acc[4 + mi][nj] = __builtin_amdgcn_mfma_f32_16x16x32_bf16(a1[mi][1], b0[nj][1], acc[4 + mi][nj], 0, 0, 0);
                acc[4 + mi][2 + nj] = __builtin_amdgcn_mfma_f32_16x16x32_bf16(a1[mi][0], b1[nj][0], acc[4 + mi][2 + nj], 0, 0, 0);
                acc[4 + mi][2 + nj] = __builtin_amdgcn_mfma_f32_16x16x32_bf16(a1[mi][1], b1[nj][1], acc[4 + mi][2 + nj], 0, 0, 0);
            }
    }
#undef STG_A
#undef STG_B
#undef VMCNT4
#undef BARF

    // ---- fused epilogue (wave owns 128 rows x 64 cols = one head's d-span) ----
    const int type = (n0 + warp_n * 64) >> 9;   // 0=q, 1=k, 2=v (uniform/wave)
    const int c  = lane & 15;
    const int g4 = (lane >> 4) * 4;
    const int mrow0 = m0 + warp_m * 128;

    if (type != 0) {                    // LN over head dim (k or v)
        const float* gamma = (type == 1) ? gk : gv;
        const float* beta  = (type == 1) ? bk : bvv;
        float gm[4], bt[4];
        #pragma unroll
        for (int j = 0; j < 4; ++j) { gm[j] = gamma[j * 16 + c]; bt[j] = beta[j * 16 + c]; }
        #pragma unroll
        for (int i = 0; i < 8; ++i)
            #pragma unroll
            for (int r = 0; r < 4; ++r) {
                float t0 = acc[i][0][r], t1 = acc[i][1][r];
                float t2 = acc[i][2][r], t3 = acc[i][3][r];
                float s  = t0 + t1 + t2 + t3;
                float ss = t0*t0 + t1*t1 + t2*t2 + t3*t3;
                #pragma unroll
                for (int msk = 1; msk < 16; msk <<= 1) {
                    s  += __shfl_xor(s,  msk, 64);
                    ss += __shfl_xor(ss, msk, 64);
                }
                const float mu = s * (1.0f / 64.0f);
                const float rs = rsqrtf(ss * (1.0f / 64.0f) - mu * mu + EPSF);
                acc[i][0][r] = (t0 - mu) * rs * gm[0] + bt[0];
                acc[i][1][r] = (t1 - mu) * rs * gm[1] + bt[1];
                acc[i][2][r] = (t2 - mu) * rs * gm[2] + bt[2];
                acc[i][3][r] = (t3 - mu) * rs * gm[3] + bt[3];
            }
    }
    if (type != 2) {                    // RoPE 2D (q or k)
        const float Kc = 64.0f * exp2f(-(float)c * L2_10K_16);
        #pragma unroll
        for (int i = 0; i < 8; ++i)
            #pragma unroll
            for (int r = 0; r < 4; ++r) {
                const int row = mrow0 + (i >> 2) * 64 + (i & 3) * 16 + g4 + r;
                const float2 p = ((const float2*)pos)[row];
                float sx, cx, sy, cy;
                __sincosf(p.x * Kc, &sx, &cx);
                __sincosf(p.y * Kc, &sy, &cy);
                const float t0 = acc[i][0][r], t1 = acc[i][1][r];
                const float t2 = acc[i][2][r], t3 = acc[i][3][r];
                acc[i][0][r] = t0 * cx - t1 * sx;
                acc[i][1][r] = t1 * cx + t0 * sx;
                acc[i][2][r] = t2 * cy - t3 * sy;
                acc[i][3][r] = t3 * cy + t2 * sy;
            }
    }
    #pragma unroll
    for (int i = 0; i < 8; ++i)
        #pragma unroll
        for (int j = 0; j < 4; ++j) {
            unsigned short* qp = qkvb
                + (size_t)(mrow0 + (i >> 2) * 64 + (i & 3) * 16 + g4) * QKVC
                + n0 + warp_n * 64 + j * 16 + c;
            #pragma unroll
            for (int r = 0; r < 4; ++r)
                qp[(size_t)r * QKVC] = f2bf(acc[i][j][r]);
        }
}

// ---------------------------------------------------------------------------
// dots[b][h][d][e] = sum_n k[b,h,n,d] * v[b,h,n,e]  (bf16 in, fp32 atomics)
// ---------------------------------------------------------------------------
__global__ __launch_bounds__(256)
void dots_kernel(const unsigned short* __restrict__ qkvb, float* __restrict__ dots)
{
    __shared__ float ks[32][64];
    __shared__ float vs[32][64];
    const int b = blockIdx.z, h = blockIdx.y;
    const int n0 = blockIdx.x * 512;
    const int t = threadIdx.x;
    const int row = t >> 3;            // 0..31
    const int c8  = (t & 7) * 8;
    const int d0 = (t >> 4) * 4;
    const int e0 = (t & 15) * 4;

    float acc[4][4] = {{0.0f}};
    const size_t kbase = (size_t)(b * NN + n0 + row) * QKVC + 512 + h * NDH + c8;
    const size_t vbase = kbase + 512;

    u16x8 ku = *(const u16x8*)(qkvb + kbase);
    u16x8 vu = *(const u16x8*)(qkvb + vbase);

    for (int s = 0; s < 16; ++s) {
        __syncthreads();
        #pragma unroll
        for (int j = 0; j < 8; ++j) {
            ks[row][c8 + j] = bf2f(ku[j]);
            vs[row][c8 + j] = bf2f(vu[j]);
        }
        __syncthreads();
        if (s + 1 < 16) {
            ku = *(const u16x8*)(qkvb + kbase + (size_t)(s + 1) * 32 * QKVC);
            vu = *(const u16x8*)(qkvb + vbase + (size_t)(s + 1) * 32 * QKVC);
        }
        #pragma unroll
        for (int r = 0; r < 32; ++r) {
            float4 kd = *(float4*)&ks[r][d0];
            float4 ve = *(float4*)&vs[r][e0];
            acc[0][0] += kd.x*ve.x; acc[0][1] += kd.x*ve.y; acc[0][2] += kd.x*ve.z; acc[0][3] += kd.x*ve.w;
            acc[1][0] += kd.y*ve.x; acc[1][1] += kd.y*ve.y; acc[1][2] += kd.y*ve.z; acc[1][3] += kd.y*ve.w;
            acc[2][0] += kd.z*ve.x; acc[2][1] += kd.z*ve.y; acc[2][2] += kd.z*ve.z; acc[2][3] += kd.z*ve.w;
            acc[3][0] += kd.w*ve.x; acc[3][1] += kd.w*ve.y; acc[3][2] += kd.w*ve.z; acc[3][3] += kd.w*ve.w;
        }
    }
    float* dp = dots + ((size_t)(b * NH + h) * 64 + d0) * 64 + e0;
    #pragma unroll
    for (int i = 0; i < 4; ++i)
        #pragma unroll
        for (int j = 0; j < 4; ++j)
            atomicAdd(dp + i * 64 + j, acc[i][j]);
}

// ---------------------------------------------------------------------------
// M2b[b][d'][h*64+d] = bf16( sum_e dots_bf[b,h,d,e] * Woutb[d', h*64+e] )
// ---------------------------------------------------------------------------
__global__ __launch_bounds__(256)
void dotsw_mfma(const unsigned short* __restrict__ Woutb,
                const unsigned short* __restrict__ dots_bf,
                unsigned short* __restrict__ M2b)
{
    __shared__ unsigned short As[128 * 64];   // Wout tile, row-major (16 KB)
    __shared__ unsigned short Bs[64 * 64];    // dots[b,h], row-major (8 KB)
    const int t = threadIdx.x;
    const int wave = t >> 6;
    const int lane = t & 63;
    const int dp0 = blockIdx.x * 128;
    const int h = blockIdx.y, b = blockIdx.z;

    const int srow = lane >> 3;               // 0..7
    const int scol = (lane & 7) * 8;
    const unsigned short* Ag = Woutb + (size_t)(dp0 + wave * 32 + srow) * NDIM
                             + h * NDH + scol;
    const unsigned short* Bg = dots_bf + ((size_t)(b * NH + h) * 64 + wave * 16 + srow) * 64
                             + scol;
    #pragma unroll
    for (int i = 0; i < 4; ++i)
        GLOAD_LDS16(Ag + (size_t)i * 8 * NDIM, As + wave * 2048 + i * 512);
    #pragma unroll
    for (int i = 0; i < 2; ++i)
        GLOAD_LDS16(Bg + (size_t)i * 8 * 64, Bs + wave * 1024 + i * 512);
    __syncthreads();

    const int wm = (wave >> 1) * 64;          // d' quadrant
    const int wn = (wave & 1) * 32;           // d half
    const int fr = lane & 15;
    const int fq = (lane >> 4) * 8;

    f32x4_t acc[4][2] = {};
    #pragma unroll
    for (int kk = 0; kk < 2; ++kk) {
        bf16x8_t af[4], bf[2];
        #pragma unroll
        for (int i = 0; i < 4; ++i)
            af[i] = *(const bf16x8_t*)&As[(wm + i * 16 + fr) * 64 + kk * 32 + fq];
        #pragma unroll
        for (int j = 0; j < 2; ++j)
            bf[j] = *(const bf16x8_t*)&Bs[(wn + j * 16 + fr) * 64 + kk * 32 + fq];
        #pragma unroll
        for (int i = 0; i < 4; ++i)
            #pragma unroll
            for (int j = 0; j < 2; ++j)
                acc[i][j] = __builtin_amdgcn_mfma_f32_16x16x32_bf16(
                    af[i], bf[j], acc[i][j], 0, 0, 0);
    }

    const int c  = lane & 15;
    const int g4 = (lane >> 4) * 4;
    #pragma unroll
    for (int i = 0; i < 4; ++i)
        #pragma unroll
        for (int j = 0; j < 2; ++j) {
            unsigned short* mp = M2b + ((size_t)(b * NDIM) + dp0 + wm + i * 16 + g4) * NDIM
                               + h * NDH + wn + j * 16 + c;
            #pragma unroll
            for (int r = 0; r < 4; ++r)
                mp[(size_t)r * NDIM] = f2bf(acc[i][j][r]);
        }
}

// ---------------------------------------------------------------------------
// out[b*NN+m][d'] = sum_hd q[b,m,hd] * M2b[b][d'][hd] + bout[d']   (fp32 out)
// ---------------------------------------------------------------------------
__global__ __launch_bounds__(256)
void gemm_out_mfma(const unsigned short* __restrict__ qkvb,
                   const unsigned short* __restrict__ M2b,
                   const float* __restrict__ bias, float* __restrict__ C)
{
    __shared__ unsigned short As[128 * 32];
    __shared__ unsigned short Bs[128 * 32];
    const int t    = threadIdx.x;
    const int wave = t >> 6;
    const int lane = t & 63;
    const int b  = blockIdx.z;
    const int m0 = b * NN + blockIdx.y * 128;
    const int n0 = blockIdx.x * 128;
    const int wm = (wave >> 1) * 64;
    const int wn = (wave & 1) * 64;
    const int K = NDIM;

    f32x4_t acc[4][4] = {};

    const int srow = wave * 32 + (lane >> 2);
    const int scol = (lane & 3) * 8;
    const unsigned short* Ag = qkvb + (size_t)(m0 + srow) * QKVC + scol;
    const unsigned short* Bg = M2b + ((size_t)b * NDIM + n0 + srow) * NDIM + scol;
    unsigned short* sA = As + wave * 1024;
    unsigned short* sB = Bs + wave * 1024;

    const int fr = lane & 15;
    const int fq = (lane >> 4) * 8;

    for (int kt = 0; kt < K; kt += 32) {
        __syncthreads();
        GLOAD_LDS16(Ag + kt,             sA);
        GLOAD_LDS16(Ag + kt + (size_t)16 * QKVC, sA + 512);
        GLOAD_LDS16(Bg + kt,             sB);
        GLOAD_LDS16(Bg + kt + 16 * NDIM, sB + 512);
        __syncthreads();

        bf16x8_t af[4], bf[4];
        #pragma unroll
        for (int i = 0; i < 4; ++i) {
            af[i] = *(const bf16x8_t*)&As[(wm + i * 16 + fr) * 32 + fq];
            bf[i] = *(const bf16x8_t*)&Bs[(wn + i * 16 + fr) * 32 + fq];
        }
        #pragma unroll
        for (int i = 0; i < 4; ++i)
            #pragma unroll
            for (int j = 0; j < 4; ++j)
                acc[i][j] = __builtin_amdgcn_mfma_f32_16x16x32_bf16(
                    af[i], bf[j], acc[i][j], 0, 0, 0);
    }

    const int crow = (lane >> 4) * 4;
    const int ccol = lane & 15;
    #pragma unroll
    for (int j = 0; j < 4; ++j) {
        const int cn = n0 + wn + j * 16 + ccol;
        const float bb = bias[cn];
        #pragma unroll
        for (int i = 0; i < 4; ++i) {
            float* cp = C + (size_t)(m0 + wm + i * 16 + crow) * NDIM + cn;
            #pragma unroll
            for (int r = 0; r < 4; ++r)
                cp[(size_t)r * NDIM] = acc[i][j][r] + bb;
        }
    }
}

// ---------------------------------------------------------------------------
extern "C" void kernel_launch(void* const* d_in, const int* in_sizes, int n_in,
                              void* d_out, int out_size, void* d_ws, size_t ws_size,
                              hipStream_t stream)
{
    const float* x    = (const float*)d_in[0];
    const float* pos  = (const float*)d_in[1];
    const float* Wqkv = (const float*)d_in[2];
    const float* gk   = (const float*)d_in[3];
    const float* bk   = (const float*)d_in[4];
    const float* gv   = (const float*)d_in[5];
    const float* bv   = (const float*)d_in[6];
    const float* Wout = (const float*)d_in[7];
    const float* bout = (const float*)d_in[8];
    float* out = (float*)d_out;

    // ws: dots f32(1M) | dots_bf(0.5M) | M2b(4M) | qkvb(96M) | xb(32M) | W(2M)
    float* dots = (float*)d_ws;
    unsigned short* dots_bf = (unsigned short*)(dots + (size_t)NB * NH * 64 * 64);
    unsigned short* M2b     = dots_bf + (size_t)NB * NH * 64 * 64;
    unsigned short* qkvb    = M2b + (size_t)NB * NDIM * NDIM;
    unsigned short* xb      = qkvb + (size_t)NROWS * QKVC;
    unsigned short* Wqkvb   = xb + (size_t)NROWS * NDIM;
    unsigned short* Woutb   = Wqkvb + (size_t)QKVC * NDIM;

    hipMemsetAsync(dots, 0, (size_t)NB * NH * 64 * 64 * sizeof(float), stream);

    dim3 blk(256);
    // 0) fp32 -> bf16 converts
    cvt_bf16_kernel<<<dim3(NROWS * NDIM / 2048), blk, 0, stream>>>(x, xb, NROWS * NDIM);
    cvt_bf16_kernel<<<dim3(QKVC * NDIM / 2048), blk, 0, stream>>>(Wqkv, Wqkvb, QKVC * NDIM);
    cvt_bf16_kernel<<<dim3(NDIM * NDIM / 2048), blk, 0, stream>>>(Wout, Woutb, NDIM * NDIM);
    // 1) qkvb = post( x @ Wqkv^T )  -- LN(k,v) + RoPE(q,k) fused, bf16 out
    //    256x256 tile, 512 threads, 4-phase/K-tile pipelined (m201 schedule)
    gemm_qkv_fused<<<dim3(QKVC / 256, NROWS / 256), dim3(512), 0, stream>>>(
        xb, Wqkvb, pos, gk, bk, gv, bv, qkvb);
    // 2) dots = k^T v per (b,h)
    dots_kernel<<<dim3(NN / 512, NH, NB), blk, 0, stream>>>(qkvb, dots);
    // 3) dots_bf = bf16(dots / N)
    cvt_dots_kernel<<<dim3(NB * NH * 64 * 64 / 1024), blk, 0, stream>>>(dots, dots_bf);
    // 4) M2b[b] = (dots_bf[b] @ blockdiag) x Wout^T  (bf16 MFMA)
    dotsw_mfma<<<dim3(NDIM / 128, NH, NB), blk, 0, stream>>>(Woutb, dots_bf, M2b);
    // 5) out = q @ M2b[b]^T + bout  (bf16 MFMA, fp32 out)
    gemm_out_mfma<<<dim3(NDIM / 128, NN / 128, NB), blk, 0, stream>>>(
        qkvb, M2b, bout, out);
}

// Round 3
// 285.696 us; speedup vs baseline: 1.1256x; 1.1256x over previous
//
#include <hip/hip_runtime.h>
#include <math.h>

#define NB 8
#define NN 4096
#define NDIM 512
#define NH 8
#define NDH 64
#define QKVC 1536
#define NROWS (NB * NN)
#define EPSF 1e-5f
#define INV_N (1.0f / 4096.0f)
// log2(10000)/16
#define L2_10K_16 0.8304820237218406f

typedef __bf16 bf16x8_t __attribute__((ext_vector_type(8)));
typedef float f32x4_t __attribute__((ext_vector_type(4)));
typedef unsigned short u16x8 __attribute__((ext_vector_type(8)));

__device__ inline unsigned short f2bf(float f) {
    unsigned u = __builtin_bit_cast(unsigned, f);
    u += 0x7fff + ((u >> 16) & 1);          // round-to-nearest-even
    return (unsigned short)(u >> 16);
}
__device__ inline float bf2f(unsigned short u) {
    unsigned v = (unsigned)u << 16;
    return __builtin_bit_cast(float, v);
}

// async global->LDS, 16B per lane; LDS dest = wave-uniform base + lane*16
#define GLOAD_LDS16(g, s) __builtin_amdgcn_global_load_lds(                    \
    (const __attribute__((address_space(1))) void*)(g),                        \
    (__attribute__((address_space(3))) void*)(s), 16, 0, 0)

// ---------------------------------------------------------------------------
// fp32 -> bf16 convert, 8 elems/thread. n must be multiple of 8.
// ---------------------------------------------------------------------------
__global__ __launch_bounds__(256)
void cvt_bf16_kernel(const float* __restrict__ s, unsigned short* __restrict__ d, int n)
{
    const int i = (blockIdx.x * 256 + threadIdx.x) * 8;
    if (i >= n) return;
    float4 a = *(const float4*)(s + i);
    float4 b = *(const float4*)(s + i + 4);
    ushort4 lo, hi;
    lo.x = f2bf(a.x); lo.y = f2bf(a.y); lo.z = f2bf(a.z); lo.w = f2bf(a.w);
    hi.x = f2bf(b.x); hi.y = f2bf(b.y); hi.z = f2bf(b.z); hi.w = f2bf(b.w);
    *(ushort4*)(d + i)     = lo;
    *(ushort4*)(d + i + 4) = hi;
}

// fp32 -> bf16 with scale (for dots -> dots_bf * 1/N), 4 elems/thread
__global__ __launch_bounds__(256)
void cvt_dots_kernel(const float* __restrict__ s, unsigned short* __restrict__ d)
{
    const int i = (blockIdx.x * 256 + threadIdx.x) * 4;
    float4 a = *(const float4*)(s + i);
    ushort4 o;
    o.x = f2bf(a.x * INV_N); o.y = f2bf(a.y * INV_N);
    o.z = f2bf(a.z * INV_N); o.w = f2bf(a.w * INV_N);
    *(ushort4*)(d + i) = o;
}

// ---------------------------------------------------------------------------
// Fused QKV GEMM, 256x256 tile, BK=64, 8 waves (2M x 4N), per-wave C 128x64.
// 4-phase/K-tile counted-vmcnt pipeline (see round-2 notes). Epilogue:
// RoPE(q,k) + LN(k,v); q -> qb [m][512] row-major; k,v -> kT/vT [b,h,d,n]
// TRANSPOSED (4 consecutive n per thread = one ushort4 store), feeding the
// MFMA dots kernel with K(=n)-contiguous operands.
// ---------------------------------------------------------------------------
__global__ __launch_bounds__(512, 2)
void gemm_qkv_fused(const unsigned short* __restrict__ A,
                    const unsigned short* __restrict__ Bm,
                    const float* __restrict__ pos,
                    const float* __restrict__ gk, const float* __restrict__ bk,
                    const float* __restrict__ gv, const float* __restrict__ bvv,
                    unsigned short* __restrict__ qb,
                    unsigned short* __restrict__ kT,
                    unsigned short* __restrict__ vT)
{
    // per buffer: A 2x[128][64] (32KB) then B 2x[128][64] (32KB); x2 = 128KB
    __shared__ __align__(16) unsigned short lds[2 * 32768];

    const int tid  = threadIdx.x;
    const int wave = tid >> 6;
    const int lane = tid & 63;

    // T1: bijective XCD swizzle (nwg = 768, 768 % 8 == 0)
    int flat = blockIdx.y * 6 + blockIdx.x;
    flat = (flat & 7) * 96 + (flat >> 3);
    const int bx = flat % 6;
    const int by = flat / 6;
    const int m0 = by * 256;
    const int n0 = bx * 256;

    const int warp_m = wave >> 2;       // 0..1 -> rows warp_m*128
    const int warp_n = wave & 3;        // 0..3 -> cols warp_n*64 (one head)
    const int fr = lane & 15;
    const int fq = lane >> 4;           // 0..3
    const int ch0 = ((fq ^ (fr & 7)) << 3);   // shorts; ks=0 chunk offset
    const int ch1 = ch0 ^ 32;                 // ks=1

    // stage source addressing (pre-swizzled global chunk, rule 21)
    const int r6 = tid >> 3;                  // 0..63 (row within 64-row call)
    const int cs = (((tid & 7) ^ (r6 & 7)) << 3);
    const unsigned short* Asrc = A  + (size_t)(m0 + r6) * NDIM + cs;
    const unsigned short* Bsrc = Bm + (size_t)(n0 + (r6 >> 5) * 64 + (r6 & 31)) * NDIM + cs;
    const int sdst = wave * 512;              // per-wave linear LDS dest (shorts)

#define STG_A(tt, h, c) GLOAD_LDS16(Asrc + (size_t)((c) * 128 + (h) * 64) * NDIM + (tt) * 64, \
        &lds[(((tt) & 1) << 15) + ((h) << 13) + ((c) << 12) + sdst])
#define STG_B(tt, h, c) GLOAD_LDS16(Bsrc + (size_t)((c) * 128 + (h) * 32) * NDIM + (tt) * 64, \
        &lds[(((tt) & 1) << 15) + 16384 + ((h) << 13) + ((c) << 12) + sdst])
#define VMCNT4 asm volatile("s_waitcnt vmcnt(4)" ::: "memory")
#define BARF   { __builtin_amdgcn_s_barrier(); asm volatile("" ::: "memory"); }

    f32x4_t acc[8][4] = {};

    // prologue: stage tile 0 in order A0,B0,B1,A1 (8 gloads)
    STG_A(0, 0, 0); STG_A(0, 0, 1);
    STG_B(0, 0, 0); STG_B(0, 0, 1);
    STG_B(0, 1, 0); STG_B(0, 1, 1);
    STG_A(0, 1, 0); STG_A(0, 1, 1);

    const unsigned short* Afr = &lds[(warp_m * 64 + fr) * 64];          // +rb +mh*8192 +mi*1024 +ch
    const unsigned short* Bfr = &lds[16384 + (warp_n * 32 + fr) * 64];  // +rb +nh*8192 +nj*1024 +ch

    bf16x8_t a0[4][2], a1[4][2], b0[2][2], b1[2][2];

    for (int tt = 0; tt < 7; ++tt) {
        const int rb = (tt & 1) << 15;
        // ---- phase 0: read A0,B0; stage A0(t+1); MFMA (m0..3 x n0..1) ----
        VMCNT4; BARF;
        #pragma unroll
        for (int mi = 0; mi < 4; ++mi) {
            a0[mi][0] = *(const bf16x8_t*)&Afr[rb + mi * 1024 + ch0];
            a0[mi][1] = *(const bf16x8_t*)&Afr[rb + mi * 1024 + ch1];
        }
        #pragma unroll
        for (int nj = 0; nj < 2; ++nj) {
            b0[nj][0] = *(const bf16x8_t*)&Bfr[rb + nj * 1024 + ch0];
            b0[nj][1] = *(const bf16x8_t*)&Bfr[rb + nj * 1024 + ch1];
        }
        STG_A(tt + 1, 0, 0); STG_A(tt + 1, 0, 1);
        __builtin_amdgcn_s_setprio(1);
        #pragma unroll
        for (int mi = 0; mi < 4; ++mi)
            #pragma unroll
            for (int nj = 0; nj < 2; ++nj) {
                acc[mi][nj] = __builtin_amdgcn_mfma_f32_16x16x32_bf16(a0[mi][0], b0[nj][0], acc[mi][nj], 0, 0, 0);
                acc[mi][nj] = __builtin_amdgcn_mfma_f32_16x16x32_bf16(a0[mi][1], b0[nj][1], acc[mi][nj], 0, 0, 0);
            }
        __builtin_amdgcn_s_setprio(0);
        // ---- phase 1: read B1; stage B0(t+1); MFMA (m0..3 x n2..3) ----
        VMCNT4; BARF;
        #pragma unroll
        for (int nj = 0; nj < 2; ++nj) {
            b1[nj][0] = *(const bf16x8_t*)&Bfr[rb + 8192 + nj * 1024 + ch0];
            b1[nj][1] = *(const bf16x8_t*)&Bfr[rb + 8192 + nj * 1024 + ch1];
        }
        STG_B(tt + 1, 0, 0); STG_B(tt + 1, 0, 1);
        __builtin_amdgcn_s_setprio(1);
        #pragma unroll
        for (int mi = 0; mi < 4; ++mi)
            #pragma unroll
            for (int nj = 0; nj < 2; ++nj) {
                acc[mi][2 + nj] = __builtin_amdgcn_mfma_f32_16x16x32_bf16(a0[mi][0], b1[nj][0], acc[mi][2 + nj], 0, 0, 0);
                acc[mi][2 + nj] = __builtin_amdgcn_mfma_f32_16x16x32_bf16(a0[mi][1], b1[nj][1], acc[mi][2 + nj], 0, 0, 0);
            }
        __builtin_amdgcn_s_setprio(0);
        // ---- phase 2: read A1; stage B1(t+1); MFMA (m4..7 x n0..1) ----
        VMCNT4; BARF;
        #pragma unroll
        for (int mi = 0; mi < 4; ++mi) {
            a1[mi][0] = *(const bf16x8_t*)&Afr[rb + 8192 + mi * 1024 + ch0];
            a1[mi][1] = *(const bf16x8_t*)&Afr[rb + 8192 + mi * 1024 + ch1];
        }
        STG_B(tt + 1, 1, 0); STG_B(tt + 1, 1, 1);
        __builtin_amdgcn_s_setprio(1);
        #pragma unroll
        for (int mi = 0; mi < 4; ++mi)
            #pragma unroll
            for (int nj = 0; nj < 2; ++nj) {
                acc[4 + mi][nj] = __builtin_amdgcn_mfma_f32_16x16x32_bf16(a1[mi][0], b0[nj][0], acc[4 + mi][nj], 0, 0, 0);
                acc[4 + mi][nj] = __builtin_amdgcn_mfma_f32_16x16x32_bf16(a1[mi][1], b0[nj][1], acc[4 + mi][nj], 0, 0, 0);
            }
        __builtin_amdgcn_s_setprio(0);
        // ---- phase 3: stage A1(t+1); MFMA (m4..7 x n2..3) (regs only) ----
        STG_A(tt + 1, 1, 0); STG_A(tt + 1, 1, 1);
        __builtin_amdgcn_s_setprio(1);
        #pragma unroll
        for (int mi = 0; mi < 4; ++mi)
            #pragma unroll
            for (int nj = 0; nj < 2; ++nj) {
                acc[4 + mi][2 + nj] = __builtin_amdgcn_mfma_f32_16x16x32_bf16(a1[mi][0], b1[nj][0], acc[4 + mi][2 + nj], 0, 0, 0);
                acc[4 + mi][2 + nj] = __builtin_amdgcn_mfma_f32_16x16x32_bf16(a1[mi][1], b1[nj][1], acc[4 + mi][2 + nj], 0, 0, 0);
            }
        __builtin_amdgcn_s_setprio(0);
    }
    // ---- final K-tile (tt=7, buffer 1): drain once, no stages/barriers ----
    {
        const int rb = 32768;
        asm volatile("s_waitcnt vmcnt(0)" ::: "memory");
        BARF;
        #pragma unroll
        for (int mi = 0; mi < 4; ++mi) {
            a0[mi][0] = *(const bf16x8_t*)&Afr[rb + mi * 1024 + ch0];
            a0[mi][1] = *(const bf16x8_t*)&Afr[rb + mi * 1024 + ch1];
        }
        #pragma unroll
        for (int nj = 0; nj < 2; ++nj) {
            b0[nj][0] = *(const bf16x8_t*)&Bfr[rb + nj * 1024 + ch0];
            b0[nj][1] = *(const bf16x8_t*)&Bfr[rb + nj * 1024 + ch1];
        }
        #pragma unroll
        for (int mi = 0; mi < 4; ++mi)
            #pragma unroll
            for (int nj = 0; nj < 2; ++nj) {
                acc[mi][nj] = __builtin_amdgcn_mfma_f32_16x16x32_bf16(a0[mi][0], b0[nj][0], acc[mi][nj], 0, 0, 0);
                acc[mi][nj] = __builtin_amdgcn_mfma_f32_16x16x32_bf16(a0[mi][1], b0[nj][1], acc[mi][nj], 0, 0, 0);
            }
        #pragma unroll
        for (int nj = 0; nj < 2; ++nj) {
            b1[nj][0] = *(const bf16x8_t*)&Bfr[rb + 8192 + nj * 1024 + ch0];
            b1[nj][1] = *(const bf16x8_t*)&Bfr[rb + 8192 + nj * 1024 + ch1];
        }
        #pragma unroll
        for (int mi = 0; mi < 4; ++mi)
            #pragma unroll
            for (int nj = 0; nj < 2; ++nj) {
                acc[mi][2 + nj] = __builtin_amdgcn_mfma_f32_16x16x32_bf16(a0[mi][0], b1[nj][0], acc[mi][2 + nj], 0, 0, 0);
                acc[mi][2 + nj] = __builtin_amdgcn_mfma_f32_16x16x32_bf16(a0[mi][1], b1[nj][1], acc[mi][2 + nj], 0, 0, 0);
            }
        #pragma unroll
        for (int mi = 0; mi < 4; ++mi) {
            a1[mi][0] = *(const bf16x8_t*)&Afr[rb + 8192 + mi * 1024 + ch0];
            a1[mi][1] = *(const bf16x8_t*)&Afr[rb + 8192 + mi * 1024 + ch1];
        }
        #pragma unroll
        for (int mi = 0; mi < 4; ++mi)
            #pragma unroll
            for (int nj = 0; nj < 2; ++nj) {
                acc[4 + mi][nj] = __builtin_amdgcn_mfma_f32_16x16x32_bf16(a1[mi][0], b0[nj][0], acc[4 + mi][nj], 0, 0, 0);
                acc[4 + mi][nj] = __builtin_amdgcn_mfma_f32_16x16x32_bf16(a1[mi][1], b0[nj][1], acc[4 + mi][nj], 0, 0, 0);
                acc[4 + mi][2 + nj] = __builtin_amdgcn_mfma_f32_16x16x32_bf16(a1[mi][0], b1[nj][0], acc[4 + mi][2 + nj], 0, 0, 0);
                acc[4 + mi][2 + nj] = __builtin_amdgcn_mfma_f32_16x16x32_bf16(a1[mi][1], b1[nj][1], acc[4 + mi][2 + nj], 0, 0, 0);
            }
    }
#undef STG_A
#undef STG_B
#undef VMCNT4
#undef BARF

    // ---- fused epilogue (wave owns 128 rows x 64 cols = one head's d-span) ----
    const int nc = n0 + warp_n * 64;            // global col base (uniform/wave)
    const int type = nc >> 9;                   // 0=q, 1=k, 2=v
    const int c  = lane & 15;
    const int g4 = (lane >> 4) * 4;
    const int mrow0 = m0 + warp_m * 128;

    if (type != 0) {                    // LN over head dim (k or v)
        const float* gamma = (type == 1) ? gk : gv;
        const float* beta  = (type == 1) ? bk : bvv;
        float gm[4], bt[4];
        #pragma unroll
        for (int j = 0; j < 4; ++j) { gm[j] = gamma[j * 16 + c]; bt[j] = beta[j * 16 + c]; }
        #pragma unroll
        for (int i = 0; i < 8; ++i)
            #pragma unroll
            for (int r = 0; r < 4; ++r) {
                float t0 = acc[i][0][r], t1 = acc[i][1][r];
                float t2 = acc[i][2][r], t3 = acc[i][3][r];
                float s  = t0 + t1 + t2 + t3;
                float ss = t0*t0 + t1*t1 + t2*t2 + t3*t3;
                #pragma unroll
                for (int msk = 1; msk < 16; msk <<= 1) {
                    s  += __shfl_xor(s,  msk, 64);
                    ss += __shfl_xor(ss, msk, 64);
                }
                const float mu = s * (1.0f / 64.0f);
                const float rs = rsqrtf(ss * (1.0f / 64.0f) - mu * mu + EPSF);
                acc[i][0][r] = (t0 - mu) * rs * gm[0] + bt[0];
                acc[i][1][r] = (t1 - mu) * rs * gm[1] + bt[1];
                acc[i][2][r] = (t2 - mu) * rs * gm[2] + bt[2];
                acc[i][3][r] = (t3 - mu) * rs * gm[3] + bt[3];
            }
    }
    if (type != 2) {                    // RoPE 2D (q or k)
        const float Kc = 64.0f * exp2f(-(float)c * L2_10K_16);
        #pragma unroll
        for (int i = 0; i < 8; ++i)
            #pragma unroll
            for (int r = 0; r < 4; ++r) {
                const int row = mrow0 + (i >> 2) * 64 + (i & 3) * 16 + g4 + r;
                const float2 p = ((const float2*)pos)[row];
                float sx, cx, sy, cy;
                __sincosf(p.x * Kc, &sx, &cx);
                __sincosf(p.y * Kc, &sy, &cy);
                const float t0 = acc[i][0][r], t1 = acc[i][1][r];
                const float t2 = acc[i][2][r], t3 = acc[i][3][r];
                acc[i][0][r] = t0 * cx - t1 * sx;
                acc[i][1][r] = t1 * cx + t0 * sx;
                acc[i][2][r] = t2 * cy - t3 * sy;
                acc[i][3][r] = t3 * cy + t2 * sy;
            }
    }
    if (type == 0) {                    // q -> qb [m][512] row-major
        #pragma unroll
        for (int i = 0; i < 8; ++i)
            #pragma unroll
            for (int j = 0; j < 4; ++j) {
                unsigned short* qp = qb
                    + (size_t)(mrow0 + (i >> 2) * 64 + (i & 3) * 16 + g4) * NDIM
                    + nc + j * 16 + c;
                #pragma unroll
                for (int r = 0; r < 4; ++r)
                    qp[(size_t)r * NDIM] = f2bf(acc[i][j][r]);
            }
    } else {                            // k/v -> kT/vT [b,h,d,n] (transposed)
        unsigned short* T = (type == 1) ? kT : vT;
        const int h = (nc >> 6) & 7;
        #pragma unroll
        for (int i = 0; i < 8; ++i) {
            const int row = mrow0 + (i >> 2) * 64 + (i & 3) * 16 + g4;
            const int bb = row >> 12;           // batch
            const int nl = row & 4095;          // n within batch (4-aligned)
            #pragma unroll
            for (int j = 0; j < 4; ++j) {
                ushort4 o;
                o.x = f2bf(acc[i][j][0]); o.y = f2bf(acc[i][j][1]);
                o.z = f2bf(acc[i][j][2]); o.w = f2bf(acc[i][j][3]);
                *(ushort4*)(T + ((size_t)((bb * NH + h) * 64 + j * 16 + c)) * NN + nl) = o;
            }
        }
    }
}

// ---------------------------------------------------------------------------
// dots[b][h][d][e] = sum_n kT[b,h,d,n] * vT[b,h,e,n]  -- MFMA NT-GEMM.
// Grid (8 n-chunks, NH, NB), 256 thr (4 waves), per wave C 32x32 (2x2 frags).
// K=512/block in 8 steps of 64; LDS [64][64] bf16 per operand, double-buffer
// (32 KB -> 4 blocks/CU, TLP hides the per-step vmcnt(0)). XOR-swizzled via
// pre-swizzled global source (rule 21). fp32 atomics out (8 blocks/tile).
// ---------------------------------------------------------------------------
__global__ __launch_bounds__(256)
void dots_mfma(const unsigned short* __restrict__ kT,
               const unsigned short* __restrict__ vT,
               float* __restrict__ dots)
{
    __shared__ __align__(16) unsigned short sk[2][64 * 64];
    __shared__ __align__(16) unsigned short sv[2][64 * 64];
    const int t = threadIdx.x;
    const int w = t >> 6, l = t & 63;
    const int bh = blockIdx.z * NH + blockIdx.y;
    const int n0 = blockIdx.x * 512;

    const int r8 = l >> 3;                     // 0..7
    const int cs = ((l & 7) ^ r8) * 8;         // swizzled source chunk (shorts)
    const unsigned short* ksrc = kT + (size_t)(bh * 64 + w * 16 + r8) * NN + n0 + cs;
    const unsigned short* vsrc = vT + (size_t)(bh * 64 + w * 16 + r8) * NN + n0 + cs;

    // wave w stages its 16 rows (2 calls of 8 rows) per operand per K-step
#define STGK(buf, kt, q) GLOAD_LDS16(ksrc + (size_t)(q) * 8 * NN + (kt), \
        &sk[buf][w * 1024 + (q) * 512])
#define STGV(buf, kt, q) GLOAD_LDS16(vsrc + (size_t)(q) * 8 * NN + (kt), \
        &sv[buf][w * 1024 + (q) * 512])

    const int fr = l & 15, fq = l >> 4;
    const int doff = (w >> 1) * 32, eoff = (w & 1) * 32;

    f32x4_t acc[2][2] = {};

    STGK(0, 0, 0); STGK(0, 0, 1); STGV(0, 0, 0); STGV(0, 0, 1);

    for (int s = 0; s < 8; ++s) {
        const int buf = s & 1;
        asm volatile("s_waitcnt vmcnt(0)" ::: "memory");
        __builtin_amdgcn_s_barrier();
        bf16x8_t ak[2][2], bv[2][2];
        #pragma unroll
        for (int di = 0; di < 2; ++di)
            #pragma unroll
            for (int ks = 0; ks < 2; ++ks)
                ak[di][ks] = *(const bf16x8_t*)
                    &sk[buf][(doff + di * 16 + fr) * 64 + (((ks * 4 + fq) ^ (fr & 7)) * 8)];
        #pragma unroll
        for (int ej = 0; ej < 2; ++ej)
            #pragma unroll
            for (int ks = 0; ks < 2; ++ks)
                bv[ej][ks] = *(const bf16x8_t*)
                    &sv[buf][(eoff + ej * 16 + fr) * 64 + (((ks * 4 + fq) ^ (fr & 7)) * 8)];
        if (s + 1 < 8) {
            const int nb = buf ^ 1, kt = (s + 1) * 64;
            STGK(nb, kt, 0); STGK(nb, kt, 1); STGV(nb, kt, 0); STGV(nb, kt, 1);
        }
        #pragma unroll
        for (int ks = 0; ks < 2; ++ks)
            #pragma unroll
            for (int di = 0; di < 2; ++di)
                #pragma unroll
                for (int ej = 0; ej < 2; ++ej)
                    acc[di][ej] = __builtin_amdgcn_mfma_f32_16x16x32_bf16(
                        ak[di][ks], bv[ej][ks], acc[di][ej], 0, 0, 0);
    }
#undef STGK
#undef STGV

    float* dp = dots + (size_t)bh * 64 * 64;
    const int cc = l & 15;
    const int rr = (l >> 4) * 4;
    #pragma unroll
    for (int di = 0; di < 2; ++di)
        #pragma unroll
        for (int ej = 0; ej < 2; ++ej)
            #pragma unroll
            for (int r = 0; r < 4; ++r)
                atomicAdd(dp + (doff + di * 16 + rr + r) * 64 + eoff + ej * 16 + cc,
                          acc[di][ej][r]);
}

// ---------------------------------------------------------------------------
// M2b[b][d'][h*64+d] = bf16( sum_e dots_bf[b,h,d,e] * Woutb[d', h*64+e] )
// ---------------------------------------------------------------------------
__global__ __launch_bounds__(256)
void dotsw_mfma(const unsigned short* __restrict__ Woutb,
                const unsigned short* __restrict__ dots_bf,
                unsigned short* __restrict__ M2b)
{
    __shared__ unsigned short As[128 * 64];   // Wout tile, row-major (16 KB)
    __shared__ unsigned short Bs[64 * 64];    // dots[b,h], row-major (8 KB)
    const int t = threadIdx.x;
    const int wave = t >> 6;
    const int lane = t & 63;
    const int dp0 = blockIdx.x * 128;
    const int h = blockIdx.y, b = blockIdx.z;

    const int srow = lane >> 3;               // 0..7
    const int scol = (lane & 7) * 8;
    const unsigned short* Ag = Woutb + (size_t)(dp0 + wave * 32 + srow) * NDIM
                             + h * NDH + scol;
    const unsigned short* Bg = dots_bf + ((size_t)(b * NH + h) * 64 + wave * 16 + srow) * 64
                             + scol;
    #pragma unroll
    for (int i = 0; i < 4; ++i)
        GLOAD_LDS16(Ag + (size_t)i * 8 * NDIM, As + wave * 2048 + i * 512);
    #pragma unroll
    for (int i = 0; i < 2; ++i)
        GLOAD_LDS16(Bg + (size_t)i * 8 * 64, Bs + wave * 1024 + i * 512);
    __syncthreads();

    const int wm = (wave >> 1) * 64;          // d' quadrant
    const int wn = (wave & 1) * 32;           // d half
    const int fr = lane & 15;
    const int fq = (lane >> 4) * 8;

    f32x4_t acc[4][2] = {};
    #pragma unroll
    for (int kk = 0; kk < 2; ++kk) {
        bf16x8_t af[4], bf[2];
        #pragma unroll
        for (int i = 0; i < 4; ++i)
            af[i] = *(const bf16x8_t*)&As[(wm + i * 16 + fr) * 64 + kk * 32 + fq];
        #pragma unroll
        for (int j = 0; j < 2; ++j)
            bf[j] = *(const bf16x8_t*)&Bs[(wn + j * 16 + fr) * 64 + kk * 32 + fq];
        #pragma unroll
        for (int i = 0; i < 4; ++i)
            #pragma unroll
            for (int j = 0; j < 2; ++j)
                acc[i][j] = __builtin_amdgcn_mfma_f32_16x16x32_bf16(
                    af[i], bf[j], acc[i][j], 0, 0, 0);
    }

    const int c  = lane & 15;
    const int g4 = (lane >> 4) * 4;
    #pragma unroll
    for (int i = 0; i < 4; ++i)
        #pragma unroll
        for (int j = 0; j < 2; ++j) {
            unsigned short* mp = M2b + ((size_t)(b * NDIM) + dp0 + wm + i * 16 + g4) * NDIM
                               + h * NDH + wn + j * 16 + c;
            #pragma unroll
            for (int r = 0; r < 4; ++r)
                mp[(size_t)r * NDIM] = f2bf(acc[i][j][r]);
        }
}

// ---------------------------------------------------------------------------
// out[b*NN+m][d'] = sum_hd q[b,m,hd] * M2b[b][d'][hd] + bout[d']   (fp32 out)
// A = qb (lda = 512), B = M2b[b] (ldb = NDIM), K = NDIM.
// ---------------------------------------------------------------------------
__global__ __launch_bounds__(256)
void gemm_out_mfma(const unsigned short* __restrict__ qb,
                   const unsigned short* __restrict__ M2b,
                   const float* __restrict__ bias, float* __restrict__ C)
{
    __shared__ unsigned short As[128 * 32];
    __shared__ unsigned short Bs[128 * 32];
    const int t    = threadIdx.x;
    const int wave = t >> 6;
    const int lane = t & 63;
    const int b  = blockIdx.z;
    const int m0 = b * NN + blockIdx.y * 128;
    const int n0 = blockIdx.x * 128;
    const int wm = (wave >> 1) * 64;
    const int wn = (wave & 1) * 64;
    const int K = NDIM;

    f32x4_t acc[4][4] = {};

    const int srow = wave * 32 + (lane >> 2);
    const int scol = (lane & 3) * 8;
    const unsigned short* Ag = qb + (size_t)(m0 + srow) * NDIM + scol;
    const unsigned short* Bg = M2b + ((size_t)b * NDIM + n0 + srow) * NDIM + scol;
    unsigned short* sA = As + wave * 1024;
    unsigned short* sB = Bs + wave * 1024;

    const int fr = lane & 15;
    const int fq = (lane >> 4) * 8;

    for (int kt = 0; kt < K; kt += 32) {
        __syncthreads();
        GLOAD_LDS16(Ag + kt,             sA);
        GLOAD_LDS16(Ag + kt + 16 * NDIM, sA + 512);
        GLOAD_LDS16(Bg + kt,             sB);
        GLOAD_LDS16(Bg + kt + 16 * NDIM, sB + 512);
        __syncthreads();

        bf16x8_t af[4], bf[4];
        #pragma unroll
        for (int i = 0; i < 4; ++i) {
            af[i] = *(const bf16x8_t*)&As[(wm + i * 16 + fr) * 32 + fq];
            bf[i] = *(const bf16x8_t*)&Bs[(wn + i * 16 + fr) * 32 + fq];
        }
        #pragma unroll
        for (int i = 0; i < 4; ++i)
            #pragma unroll
            for (int j = 0; j < 4; ++j)
                acc[i][j] = __builtin_amdgcn_mfma_f32_16x16x32_bf16(
                    af[i], bf[j], acc[i][j], 0, 0, 0);
    }

    const int crow = (lane >> 4) * 4;
    const int ccol = lane & 15;
    #pragma unroll
    for (int j = 0; j < 4; ++j) {
        const int cn = n0 + wn + j * 16 + ccol;
        const float bb = bias[cn];
        #pragma unroll
        for (int i = 0; i < 4; ++i) {
            float* cp = C + (size_t)(m0 + wm + i * 16 + crow) * NDIM + cn;
            #pragma unroll
            for (int r = 0; r < 4; ++r)
                cp[(size_t)r * NDIM] = acc[i][j][r] + bb;
        }
    }
}

// ---------------------------------------------------------------------------
extern "C" void kernel_launch(void* const* d_in, const int* in_sizes, int n_in,
                              void* d_out, int out_size, void* d_ws, size_t ws_size,
                              hipStream_t stream)
{
    const float* x    = (const float*)d_in[0];
    const float* pos  = (const float*)d_in[1];
    const float* Wqkv = (const float*)d_in[2];
    const float* gk   = (const float*)d_in[3];
    const float* bk   = (const float*)d_in[4];
    const float* gv   = (const float*)d_in[5];
    const float* bv   = (const float*)d_in[6];
    const float* Wout = (const float*)d_in[7];
    const float* bout = (const float*)d_in[8];
    float* out = (float*)d_out;

    // ws: dots f32(1M) | dots_bf(.5M) | M2b(4M) | qb(32M) | kT(32M) | vT(32M)
    //     | xb(32M) | Wqkvb(1.5M) | Woutb(.5M)   -- ~135.5 MB total
    float* dots = (float*)d_ws;
    unsigned short* dots_bf = (unsigned short*)(dots + (size_t)NB * NH * 64 * 64);
    unsigned short* M2b     = dots_bf + (size_t)NB * NH * 64 * 64;
    unsigned short* qb      = M2b + (size_t)NB * NDIM * NDIM;
    unsigned short* kT      = qb + (size_t)NROWS * NDIM;
    unsigned short* vT      = kT + (size_t)NB * NH * NDH * NN;
    unsigned short* xb      = vT + (size_t)NB * NH * NDH * NN;
    unsigned short* Wqkvb   = xb + (size_t)NROWS * NDIM;
    unsigned short* Woutb   = Wqkvb + (size_t)QKVC * NDIM;

    hipMemsetAsync(dots, 0, (size_t)NB * NH * 64 * 64 * sizeof(float), stream);

    dim3 blk(256);
    // 0) fp32 -> bf16 converts
    cvt_bf16_kernel<<<dim3(NROWS * NDIM / 2048), blk, 0, stream>>>(x, xb, NROWS * NDIM);
    cvt_bf16_kernel<<<dim3(QKVC * NDIM / 2048), blk, 0, stream>>>(Wqkv, Wqkvb, QKVC * NDIM);
    cvt_bf16_kernel<<<dim3(NDIM * NDIM / 2048), blk, 0, stream>>>(Wout, Woutb, NDIM * NDIM);
    // 1) q -> qb, k/v -> kT/vT (transposed), LN+RoPE fused
    gemm_qkv_fused<<<dim3(QKVC / 256, NROWS / 256), dim3(512), 0, stream>>>(
        xb, Wqkvb, pos, gk, bk, gv, bv, qb, kT, vT);
    // 2) dots = k^T v per (b,h)  -- MFMA
    dots_mfma<<<dim3(NN / 512, NH, NB), blk, 0, stream>>>(kT, vT, dots);
    // 3) dots_bf = bf16(dots / N)
    cvt_dots_kernel<<<dim3(NB * NH * 64 * 64 / 1024), blk, 0, stream>>>(dots, dots_bf);
    // 4) M2b[b] = (dots_bf[b] @ blockdiag) x Wout^T  (bf16 MFMA)
    dotsw_mfma<<<dim3(NDIM / 128, NH, NB), blk, 0, stream>>>(Woutb, dots_bf, M2b);
    // 5) out = q @ M2b[b]^T + bout  (bf16 MFMA, fp32 out)
    gemm_out_mfma<<<dim3(NDIM / 128, NN / 128, NB), blk, 0, stream>>>(
        qb, M2b, bout, out);
}

// Round 4
// 278.013 us; speedup vs baseline: 1.1568x; 1.0276x over previous
//
#include <hip/hip_runtime.h>
#include <math.h>

#define NB 8
#define NN 4096
#define NDIM 512
#define NH 8
#define NDH 64
#define QKVC 1536
#define NROWS (NB * NN)
#define EPSF 1e-5f
#define INV_N (1.0f / 4096.0f)
// log2(10000)/16
#define L2_10K_16 0.8304820237218406f

typedef __bf16 bf16x8_t __attribute__((ext_vector_type(8)));
typedef float f32x4_t __attribute__((ext_vector_type(4)));
typedef unsigned short u16x8 __attribute__((ext_vector_type(8)));

__device__ inline unsigned short f2bf(float f) {
    unsigned u = __builtin_bit_cast(unsigned, f);
    u += 0x7fff + ((u >> 16) & 1);          // round-to-nearest-even
    return (unsigned short)(u >> 16);
}
__device__ inline float bf2f(unsigned short u) {
    unsigned v = (unsigned)u << 16;
    return __builtin_bit_cast(float, v);
}

// async global->LDS, 16B per lane; LDS dest = wave-uniform base + lane*16
#define GLOAD_LDS16(g, s) __builtin_amdgcn_global_load_lds(                    \
    (const __attribute__((address_space(1))) void*)(g),                        \
    (__attribute__((address_space(3))) void*)(s), 16, 0, 0)

// ---------------------------------------------------------------------------
// One kernel: fp32->bf16 for x / Wqkv / Wout, plus zeroing dots.
// Saves 3 stream ops vs separate converts + memset (launch overhead ~10us ea).
// ---------------------------------------------------------------------------
__device__ inline void cvt8v(const float* __restrict__ s,
                             unsigned short* __restrict__ d, int i)
{
    float4 a = *(const float4*)(s + i);
    float4 b = *(const float4*)(s + i + 4);
    ushort4 lo, hi;
    lo.x = f2bf(a.x); lo.y = f2bf(a.y); lo.z = f2bf(a.z); lo.w = f2bf(a.w);
    hi.x = f2bf(b.x); hi.y = f2bf(b.y); hi.z = f2bf(b.z); hi.w = f2bf(b.w);
    *(ushort4*)(d + i)     = lo;
    *(ushort4*)(d + i + 4) = hi;
}

__global__ __launch_bounds__(256)
void cvt_all(const float* __restrict__ x,  const float* __restrict__ wq,
             const float* __restrict__ wo,
             unsigned short* __restrict__ xb, unsigned short* __restrict__ wqb,
             unsigned short* __restrict__ wob, float* __restrict__ dots)
{
    const int bid = blockIdx.x, t = threadIdx.x;
    if (bid < 8192) {                       // x: 16.78M elems
        cvt8v(x, xb, (bid * 256 + t) * 8);
    } else if (bid < 8576) {                // Wqkv: 786432 elems
        cvt8v(wq, wqb, ((bid - 8192) * 256 + t) * 8);
    } else if (bid < 8704) {                // Wout: 262144 elems
        cvt8v(wo, wob, ((bid - 8576) * 256 + t) * 8);
    } else {                                // zero dots: 262144 floats
        const float4 z = {0.f, 0.f, 0.f, 0.f};
        float4* dp = (float4*)dots + (size_t)((bid - 8704) * 256 + t) * 4;
        dp[0] = z; dp[1] = z; dp[2] = z; dp[3] = z;
    }
}

// ---------------------------------------------------------------------------
// Fused QKV GEMM, 256x256 tile, BK=64, 8 waves (2M x 4N), per-wave C 128x64.
// 4-phase/K-tile counted-vmcnt pipeline (see round-2 notes). Epilogue:
// RoPE(q,k) + LN(k,v); q -> qb [m][512] row-major; k,v -> kT/vT [b,h,d,n]
// TRANSPOSED (4 consecutive n per thread = one ushort4 store), feeding the
// MFMA dots kernel with K(=n)-contiguous operands.
// ---------------------------------------------------------------------------
__global__ __launch_bounds__(512, 2)
void gemm_qkv_fused(const unsigned short* __restrict__ A,
                    const unsigned short* __restrict__ Bm,
                    const float* __restrict__ pos,
                    const float* __restrict__ gk, const float* __restrict__ bk,
                    const float* __restrict__ gv, const float* __restrict__ bvv,
                    unsigned short* __restrict__ qb,
                    unsigned short* __restrict__ kT,
                    unsigned short* __restrict__ vT)
{
    // per buffer: A 2x[128][64] (32KB) then B 2x[128][64] (32KB); x2 = 128KB
    __shared__ __align__(16) unsigned short lds[2 * 32768];

    const int tid  = threadIdx.x;
    const int wave = tid >> 6;
    const int lane = tid & 63;

    // T1: bijective XCD swizzle (nwg = 768, 768 % 8 == 0)
    int flat = blockIdx.y * 6 + blockIdx.x;
    flat = (flat & 7) * 96 + (flat >> 3);
    const int bx = flat % 6;
    const int by = flat / 6;
    const int m0 = by * 256;
    const int n0 = bx * 256;

    const int warp_m = wave >> 2;       // 0..1 -> rows warp_m*128
    const int warp_n = wave & 3;        // 0..3 -> cols warp_n*64 (one head)
    const int fr = lane & 15;
    const int fq = lane >> 4;           // 0..3
    const int ch0 = ((fq ^ (fr & 7)) << 3);   // shorts; ks=0 chunk offset
    const int ch1 = ch0 ^ 32;                 // ks=1

    // stage source addressing (pre-swizzled global chunk, rule 21)
    const int r6 = tid >> 3;                  // 0..63 (row within 64-row call)
    const int cs = (((tid & 7) ^ (r6 & 7)) << 3);
    const unsigned short* Asrc = A  + (size_t)(m0 + r6) * NDIM + cs;
    const unsigned short* Bsrc = Bm + (size_t)(n0 + (r6 >> 5) * 64 + (r6 & 31)) * NDIM + cs;
    const int sdst = wave * 512;              // per-wave linear LDS dest (shorts)

#define STG_A(tt, h, c) GLOAD_LDS16(Asrc + (size_t)((c) * 128 + (h) * 64) * NDIM + (tt) * 64, \
        &lds[(((tt) & 1) << 15) + ((h) << 13) + ((c) << 12) + sdst])
#define STG_B(tt, h, c) GLOAD_LDS16(Bsrc + (size_t)((c) * 128 + (h) * 32) * NDIM + (tt) * 64, \
        &lds[(((tt) & 1) << 15) + 16384 + ((h) << 13) + ((c) << 12) + sdst])
#define VMCNT4 asm volatile("s_waitcnt vmcnt(4)" ::: "memory")
#define BARF   { __builtin_amdgcn_s_barrier(); asm volatile("" ::: "memory"); }

    f32x4_t acc[8][4] = {};

    // prologue: stage tile 0 in order A0,B0,B1,A1 (8 gloads)
    STG_A(0, 0, 0); STG_A(0, 0, 1);
    STG_B(0, 0, 0); STG_B(0, 0, 1);
    STG_B(0, 1, 0); STG_B(0, 1, 1);
    STG_A(0, 1, 0); STG_A(0, 1, 1);

    const unsigned short* Afr = &lds[(warp_m * 64 + fr) * 64];          // +rb +mh*8192 +mi*1024 +ch
    const unsigned short* Bfr = &lds[16384 + (warp_n * 32 + fr) * 64];  // +rb +nh*8192 +nj*1024 +ch

    bf16x8_t a0[4][2], a1[4][2], b0[2][2], b1[2][2];

    for (int tt = 0; tt < 7; ++tt) {
        const int rb = (tt & 1) << 15;
        // ---- phase 0: read A0,B0; stage A0(t+1); MFMA (m0..3 x n0..1) ----
        VMCNT4; BARF;
        #pragma unroll
        for (int mi = 0; mi < 4; ++mi) {
            a0[mi][0] = *(const bf16x8_t*)&Afr[rb + mi * 1024 + ch0];
            a0[mi][1] = *(const bf16x8_t*)&Afr[rb + mi * 1024 + ch1];
        }
        #pragma unroll
        for (int nj = 0; nj < 2; ++nj) {
            b0[nj][0] = *(const bf16x8_t*)&Bfr[rb + nj * 1024 + ch0];
            b0[nj][1] = *(const bf16x8_t*)&Bfr[rb + nj * 1024 + ch1];
        }
        STG_A(tt + 1, 0, 0); STG_A(tt + 1, 0, 1);
        __builtin_amdgcn_s_setprio(1);
        #pragma unroll
        for (int mi = 0; mi < 4; ++mi)
            #pragma unroll
            for (int nj = 0; nj < 2; ++nj) {
                acc[mi][nj] = __builtin_amdgcn_mfma_f32_16x16x32_bf16(a0[mi][0], b0[nj][0], acc[mi][nj], 0, 0, 0);
                acc[mi][nj] = __builtin_amdgcn_mfma_f32_16x16x32_bf16(a0[mi][1], b0[nj][1], acc[mi][nj], 0, 0, 0);
            }
        __builtin_amdgcn_s_setprio(0);
        // ---- phase 1: read B1; stage B0(t+1); MFMA (m0..3 x n2..3) ----
        VMCNT4; BARF;
        #pragma unroll
        for (int nj = 0; nj < 2; ++nj) {
            b1[nj][0] = *(const bf16x8_t*)&Bfr[rb + 8192 + nj * 1024 + ch0];
            b1[nj][1] = *(const bf16x8_t*)&Bfr[rb + 8192 + nj * 1024 + ch1];
        }
        STG_B(tt + 1, 0, 0); STG_B(tt + 1, 0, 1);
        __builtin_amdgcn_s_setprio(1);
        #pragma unroll
        for (int mi = 0; mi < 4; ++mi)
            #pragma unroll
            for (int nj = 0; nj < 2; ++nj) {
                acc[mi][2 + nj] = __builtin_amdgcn_mfma_f32_16x16x32_bf16(a0[mi][0], b1[nj][0], acc[mi][2 + nj], 0, 0, 0);
                acc[mi][2 + nj] = __builtin_amdgcn_mfma_f32_16x16x32_bf16(a0[mi][1], b1[nj][1], acc[mi][2 + nj], 0, 0, 0);
            }
        __builtin_amdgcn_s_setprio(0);
        // ---- phase 2: read A1; stage B1(t+1); MFMA (m4..7 x n0..1) ----
        VMCNT4; BARF;
        #pragma unroll
        for (int mi = 0; mi < 4; ++mi) {
            a1[mi][0] = *(const bf16x8_t*)&Afr[rb + 8192 + mi * 1024 + ch0];
            a1[mi][1] = *(const bf16x8_t*)&Afr[rb + 8192 + mi * 1024 + ch1];
        }
        STG_B(tt + 1, 1, 0); STG_B(tt + 1, 1, 1);
        __builtin_amdgcn_s_setprio(1);
        #pragma unroll
        for (int mi = 0; mi < 4; ++mi)
            #pragma unroll
            for (int nj = 0; nj < 2; ++nj) {
                acc[4 + mi][nj] = __builtin_amdgcn_mfma_f32_16x16x32_bf16(a1[mi][0], b0[nj][0], acc[4 + mi][nj], 0, 0, 0);
                acc[4 + mi][nj] = __builtin_amdgcn_mfma_f32_16x16x32_bf16(a1[mi][1], b0[nj][1], acc[4 + mi][nj], 0, 0, 0);
            }
        __builtin_amdgcn_s_setprio(0);
        // ---- phase 3: stage A1(t+1); MFMA (m4..7 x n2..3) (regs only) ----
        STG_A(tt + 1, 1, 0); STG_A(tt + 1, 1, 1);
        __builtin_amdgcn_s_setprio(1);
        #pragma unroll
        for (int mi = 0; mi < 4; ++mi)
            #pragma unroll
            for (int nj = 0; nj < 2; ++nj) {
                acc[4 + mi][2 + nj] = __builtin_amdgcn_mfma_f32_16x16x32_bf16(a1[mi][0], b1[nj][0], acc[4 + mi][2 + nj], 0, 0, 0);
                acc[4 + mi][2 + nj] = __builtin_amdgcn_mfma_f32_16x16x32_bf16(a1[mi][1], b1[nj][1], acc[4 + mi][2 + nj], 0, 0, 0);
            }
        __builtin_amdgcn_s_setprio(0);
    }
    // ---- final K-tile (tt=7, buffer 1): drain once, no stages/barriers ----
    {
        const int rb = 32768;
        asm volatile("s_waitcnt vmcnt(0)" ::: "memory");
        BARF;
        #pragma unroll
        for (int mi = 0; mi < 4; ++mi) {
            a0[mi][0] = *(const bf16x8_t*)&Afr[rb + mi * 1024 + ch0];
            a0[mi][1] = *(const bf16x8_t*)&Afr[rb + mi * 1024 + ch1];
        }
        #pragma unroll
        for (int nj = 0; nj < 2; ++nj) {
            b0[nj][0] = *(const bf16x8_t*)&Bfr[rb + nj * 1024 + ch0];
            b0[nj][1] = *(const bf16x8_t*)&Bfr[rb + nj * 1024 + ch1];
        }
        #pragma unroll
        for (int mi = 0; mi < 4; ++mi)
            #pragma unroll
            for (int nj = 0; nj < 2; ++nj) {
                acc[mi][nj] = __builtin_amdgcn_mfma_f32_16x16x32_bf16(a0[mi][0], b0[nj][0], acc[mi][nj], 0, 0, 0);
                acc[mi][nj] = __builtin_amdgcn_mfma_f32_16x16x32_bf16(a0[mi][1], b0[nj][1], acc[mi][nj], 0, 0, 0);
            }
        #pragma unroll
        for (int nj = 0; nj < 2; ++nj) {
            b1[nj][0] = *(const bf16x8_t*)&Bfr[rb + 8192 + nj * 1024 + ch0];
            b1[nj][1] = *(const bf16x8_t*)&Bfr[rb + 8192 + nj * 1024 + ch1];
        }
        #pragma unroll
        for (int mi = 0; mi < 4; ++mi)
            #pragma unroll
            for (int nj = 0; nj < 2; ++nj) {
                acc[mi][2 + nj] = __builtin_amdgcn_mfma_f32_16x16x32_bf16(a0[mi][0], b1[nj][0], acc[mi][2 + nj], 0, 0, 0);
                acc[mi][2 + nj] = __builtin_amdgcn_mfma_f32_16x16x32_bf16(a0[mi][1], b1[nj][1], acc[mi][2 + nj], 0, 0, 0);
            }
        #pragma unroll
        for (int mi = 0; mi < 4; ++mi) {
            a1[mi][0] = *(const bf16x8_t*)&Afr[rb + 8192 + mi * 1024 + ch0];
            a1[mi][1] = *(const bf16x8_t*)&Afr[rb + 8192 + mi * 1024 + ch1];
        }
        #pragma unroll
        for (int mi = 0; mi < 4; ++mi)
            #pragma unroll
            for (int nj = 0; nj < 2; ++nj) {
                acc[4 + mi][nj] = __builtin_amdgcn_mfma_f32_16x16x32_bf16(a1[mi][0], b0[nj][0], acc[4 + mi][nj], 0, 0, 0);
                acc[4 + mi][nj] = __builtin_amdgcn_mfma_f32_16x16x32_bf16(a1[mi][1], b0[nj][1], acc[4 + mi][nj], 0, 0, 0);
                acc[4 + mi][2 + nj] = __builtin_amdgcn_mfma_f32_16x16x32_bf16(a1[mi][0], b1[nj][0], acc[4 + mi][2 + nj], 0, 0, 0);
                acc[4 + mi][2 + nj] = __builtin_amdgcn_mfma_f32_16x16x32_bf16(a1[mi][1], b1[nj][1], acc[4 + mi][2 + nj], 0, 0, 0);
            }
    }
#undef STG_A
#undef STG_B
#undef VMCNT4
#undef BARF

    // ---- fused epilogue (wave owns 128 rows x 64 cols = one head's d-span) ----
    const int nc = n0 + warp_n * 64;            // global col base (uniform/wave)
    const int type = nc >> 9;                   // 0=q, 1=k, 2=v
    const int c  = lane & 15;
    const int g4 = (lane >> 4) * 4;
    const int mrow0 = m0 + warp_m * 128;

    if (type != 0) {                    // LN over head dim (k or v)
        const float* gamma = (type == 1) ? gk : gv;
        const float* beta  = (type == 1) ? bk : bvv;
        float gm[4], bt[4];
        #pragma unroll
        for (int j = 0; j < 4; ++j) { gm[j] = gamma[j * 16 + c]; bt[j] = beta[j * 16 + c]; }
        #pragma unroll
        for (int i = 0; i < 8; ++i)
            #pragma unroll
            for (int r = 0; r < 4; ++r) {
                float t0 = acc[i][0][r], t1 = acc[i][1][r];
                float t2 = acc[i][2][r], t3 = acc[i][3][r];
                float s  = t0 + t1 + t2 + t3;
                float ss = t0*t0 + t1*t1 + t2*t2 + t3*t3;
                #pragma unroll
                for (int msk = 1; msk < 16; msk <<= 1) {
                    s  += __shfl_xor(s,  msk, 64);
                    ss += __shfl_xor(ss, msk, 64);
                }
                const float mu = s * (1.0f / 64.0f);
                const float rs = rsqrtf(ss * (1.0f / 64.0f) - mu * mu + EPSF);
                acc[i][0][r] = (t0 - mu) * rs * gm[0] + bt[0];
                acc[i][1][r] = (t1 - mu) * rs * gm[1] + bt[1];
                acc[i][2][r] = (t2 - mu) * rs * gm[2] + bt[2];
                acc[i][3][r] = (t3 - mu) * rs * gm[3] + bt[3];
            }
    }
    if (type != 2) {                    // RoPE 2D (q or k)
        const float Kc = 64.0f * exp2f(-(float)c * L2_10K_16);
        #pragma unroll
        for (int i = 0; i < 8; ++i)
            #pragma unroll
            for (int r = 0; r < 4; ++r) {
                const int row = mrow0 + (i >> 2) * 64 + (i & 3) * 16 + g4 + r;
                const float2 p = ((const float2*)pos)[row];
                float sx, cx, sy, cy;
                __sincosf(p.x * Kc, &sx, &cx);
                __sincosf(p.y * Kc, &sy, &cy);
                const float t0 = acc[i][0][r], t1 = acc[i][1][r];
                const float t2 = acc[i][2][r], t3 = acc[i][3][r];
                acc[i][0][r] = t0 * cx - t1 * sx;
                acc[i][1][r] = t1 * cx + t0 * sx;
                acc[i][2][r] = t2 * cy - t3 * sy;
                acc[i][3][r] = t3 * cy + t2 * sy;
            }
    }
    if (type == 0) {                    // q -> qb [m][512] row-major
        #pragma unroll
        for (int i = 0; i < 8; ++i)
            #pragma unroll
            for (int j = 0; j < 4; ++j) {
                unsigned short* qp = qb
                    + (size_t)(mrow0 + (i >> 2) * 64 + (i & 3) * 16 + g4) * NDIM
                    + nc + j * 16 + c;
                #pragma unroll
                for (int r = 0; r < 4; ++r)
                    qp[(size_t)r * NDIM] = f2bf(acc[i][j][r]);
            }
    } else {                            // k/v -> kT/vT [b,h,d,n] (transposed)
        unsigned short* T = (type == 1) ? kT : vT;
        const int h = (nc >> 6) & 7;
        #pragma unroll
        for (int i = 0; i < 8; ++i) {
            const int row = mrow0 + (i >> 2) * 64 + (i & 3) * 16 + g4;
            const int bb = row >> 12;           // batch
            const int nl = row & 4095;          // n within batch (4-aligned)
            #pragma unroll
            for (int j = 0; j < 4; ++j) {
                ushort4 o;
                o.x = f2bf(acc[i][j][0]); o.y = f2bf(acc[i][j][1]);
                o.z = f2bf(acc[i][j][2]); o.w = f2bf(acc[i][j][3]);
                *(ushort4*)(T + ((size_t)((bb * NH + h) * 64 + j * 16 + c)) * NN + nl) = o;
            }
        }
    }
}

// ---------------------------------------------------------------------------
// dots[b][h][d][e] = sum_n kT[b,h,d,n] * vT[b,h,e,n]  -- MFMA NT-GEMM.
// Grid (8 n-chunks, NH, NB), 256 thr (4 waves), per wave C 32x32 (2x2 frags).
// fp32 atomics out (8 blocks/tile).
// ---------------------------------------------------------------------------
__global__ __launch_bounds__(256)
void dots_mfma(const unsigned short* __restrict__ kT,
               const unsigned short* __restrict__ vT,
               float* __restrict__ dots)
{
    __shared__ __align__(16) unsigned short sk[2][64 * 64];
    __shared__ __align__(16) unsigned short sv[2][64 * 64];
    const int t = threadIdx.x;
    const int w = t >> 6, l = t & 63;
    const int bh = blockIdx.z * NH + blockIdx.y;
    const int n0 = blockIdx.x * 512;

    const int r8 = l >> 3;                     // 0..7
    const int cs = ((l & 7) ^ r8) * 8;         // swizzled source chunk (shorts)
    const unsigned short* ksrc = kT + (size_t)(bh * 64 + w * 16 + r8) * NN + n0 + cs;
    const unsigned short* vsrc = vT + (size_t)(bh * 64 + w * 16 + r8) * NN + n0 + cs;

    // wave w stages its 16 rows (2 calls of 8 rows) per operand per K-step
#define STGK(buf, kt, q) GLOAD_LDS16(ksrc + (size_t)(q) * 8 * NN + (kt), \
        &sk[buf][w * 1024 + (q) * 512])
#define STGV(buf, kt, q) GLOAD_LDS16(vsrc + (size_t)(q) * 8 * NN + (kt), \
        &sv[buf][w * 1024 + (q) * 512])

    const int fr = l & 15, fq = l >> 4;
    const int doff = (w >> 1) * 32, eoff = (w & 1) * 32;

    f32x4_t acc[2][2] = {};

    STGK(0, 0, 0); STGK(0, 0, 1); STGV(0, 0, 0); STGV(0, 0, 1);

    for (int s = 0; s < 8; ++s) {
        const int buf = s & 1;
        asm volatile("s_waitcnt vmcnt(0)" ::: "memory");
        __builtin_amdgcn_s_barrier();
        bf16x8_t ak[2][2], bv[2][2];
        #pragma unroll
        for (int di = 0; di < 2; ++di)
            #pragma unroll
            for (int ks = 0; ks < 2; ++ks)
                ak[di][ks] = *(const bf16x8_t*)
                    &sk[buf][(doff + di * 16 + fr) * 64 + (((ks * 4 + fq) ^ (fr & 7)) * 8)];
        #pragma unroll
        for (int ej = 0; ej < 2; ++ej)
            #pragma unroll
            for (int ks = 0; ks < 2; ++ks)
                bv[ej][ks] = *(const bf16x8_t*)
                    &sv[buf][(eoff + ej * 16 + fr) * 64 + (((ks * 4 + fq) ^ (fr & 7)) * 8)];
        if (s + 1 < 8) {
            const int nb = buf ^ 1, kt = (s + 1) * 64;
            STGK(nb, kt, 0); STGK(nb, kt, 1); STGV(nb, kt, 0); STGV(nb, kt, 1);
        }
        #pragma unroll
        for (int ks = 0; ks < 2; ++ks)
            #pragma unroll
            for (int di = 0; di < 2; ++di)
                #pragma unroll
                for (int ej = 0; ej < 2; ++ej)
                    acc[di][ej] = __builtin_amdgcn_mfma_f32_16x16x32_bf16(
                        ak[di][ks], bv[ej][ks], acc[di][ej], 0, 0, 0);
    }
#undef STGK
#undef STGV

    float* dp = dots + (size_t)bh * 64 * 64;
    const int cc = l & 15;
    const int rr = (l >> 4) * 4;
    #pragma unroll
    for (int di = 0; di < 2; ++di)
        #pragma unroll
        for (int ej = 0; ej < 2; ++ej)
            #pragma unroll
            for (int r = 0; r < 4; ++r)
                atomicAdd(dp + (doff + di * 16 + rr + r) * 64 + eoff + ej * 16 + cc,
                          acc[di][ej][r]);
}

// ---------------------------------------------------------------------------
// M2b[b][d'][h*64+d] = bf16( sum_e (dots[b,h,d,e]/N) * Woutb[d', h*64+e] )
// fp32 dots read + scale + bf16 convert fused into the B-tile LDS fill
// (replaces the separate cvt_dots launch).
// ---------------------------------------------------------------------------
__global__ __launch_bounds__(256)
void dotsw_mfma(const unsigned short* __restrict__ Woutb,
                const float* __restrict__ dots,
                unsigned short* __restrict__ M2b)
{
    __shared__ unsigned short As[128 * 64];   // Wout tile, row-major (16 KB)
    __shared__ unsigned short Bs[64 * 64];    // dots[b,h] bf16, row-major (8 KB)
    const int t = threadIdx.x;
    const int wave = t >> 6;
    const int lane = t & 63;
    const int dp0 = blockIdx.x * 128;
    const int h = blockIdx.y, b = blockIdx.z;

    const int srow = lane >> 3;               // 0..7
    const int scol = (lane & 7) * 8;
    const unsigned short* Ag = Woutb + (size_t)(dp0 + wave * 32 + srow) * NDIM
                             + h * NDH + scol;
    #pragma unroll
    for (int i = 0; i < 4; ++i)
        GLOAD_LDS16(Ag + (size_t)i * 8 * NDIM, As + wave * 2048 + i * 512);

    // B tile: read fp32 dots, scale by 1/N, convert to bf16 into Bs
    {
        const float* Dg = dots + (size_t)(b * NH + h) * 4096;
        const int dr = t >> 2;                // 0..63
        const int dc = (t & 3) * 16;          // 0,16,32,48
        const float* dgp = Dg + dr * 64 + dc;
        float4 f0 = *(const float4*)(dgp);
        float4 f1 = *(const float4*)(dgp + 4);
        float4 f2 = *(const float4*)(dgp + 8);
        float4 f3 = *(const float4*)(dgp + 12);
        ushort4 o0, o1, o2, o3;
        o0.x = f2bf(f0.x * INV_N); o0.y = f2bf(f0.y * INV_N);
        o0.z = f2bf(f0.z * INV_N); o0.w = f2bf(f0.w * INV_N);
        o1.x = f2bf(f1.x * INV_N); o1.y = f2bf(f1.y * INV_N);
        o1.z = f2bf(f1.z * INV_N); o1.w = f2bf(f1.w * INV_N);
        o2.x = f2bf(f2.x * INV_N); o2.y = f2bf(f2.y * INV_N);
        o2.z = f2bf(f2.z * INV_N); o2.w = f2bf(f2.w * INV_N);
        o3.x = f2bf(f3.x * INV_N); o3.y = f2bf(f3.y * INV_N);
        o3.z = f2bf(f3.z * INV_N); o3.w = f2bf(f3.w * INV_N);
        *(ushort4*)&Bs[dr * 64 + dc]      = o0;
        *(ushort4*)&Bs[dr * 64 + dc + 4]  = o1;
        *(ushort4*)&Bs[dr * 64 + dc + 8]  = o2;
        *(ushort4*)&Bs[dr * 64 + dc + 12] = o3;
    }
    __syncthreads();

    const int wm = (wave >> 1) * 64;          // d' quadrant
    const int wn = (wave & 1) * 32;           // d half
    const int fr = lane & 15;
    const int fq = (lane >> 4) * 8;

    f32x4_t acc[4][2] = {};
    #pragma unroll
    for (int kk = 0; kk < 2; ++kk) {
        bf16x8_t af[4], bf[2];
        #pragma unroll
        for (int i = 0; i < 4; ++i)
            af[i] = *(const bf16x8_t*)&As[(wm + i * 16 + fr) * 64 + kk * 32 + fq];
        #pragma unroll
        for (int j = 0; j < 2; ++j)
            bf[j] = *(const bf16x8_t*)&Bs[(wn + j * 16 + fr) * 64 + kk * 32 + fq];
        #pragma unroll
        for (int i = 0; i < 4; ++i)
            #pragma unroll
            for (int j = 0; j < 2; ++j)
                acc[i][j] = __builtin_amdgcn_mfma_f32_16x16x32_bf16(
                    af[i], bf[j], acc[i][j], 0, 0, 0);
    }

    const int c  = lane & 15;
    const int g4 = (lane >> 4) * 4;
    #pragma unroll
    for (int i = 0; i < 4; ++i)
        #pragma unroll
        for (int j = 0; j < 2; ++j) {
            unsigned short* mp = M2b + ((size_t)(b * NDIM) + dp0 + wm + i * 16 + g4) * NDIM
                               + h * NDH + wn + j * 16 + c;
            #pragma unroll
            for (int r = 0; r < 4; ++r)
                mp[(size_t)r * NDIM] = f2bf(acc[i][j][r]);
        }
}

// ---------------------------------------------------------------------------
// out[m][d'] = sum_hd q[m,hd] * M2b[b][d'][hd] + bout[d']   (fp32 out)
// 256x256 tile, 4-phase counted-vmcnt pipeline (same core as gemm_qkv_fused;
// both A and B strides are NDIM=512). Grid 2 x 128 = 256 blocks = 1/CU.
// ---------------------------------------------------------------------------
__global__ __launch_bounds__(512, 2)
void gemm_out_mfma256(const unsigned short* __restrict__ qb,
                      const unsigned short* __restrict__ M2b,
                      const float* __restrict__ bias, float* __restrict__ C)
{
    __shared__ __align__(16) unsigned short lds[2 * 32768];

    const int tid  = threadIdx.x;
    const int wave = tid >> 6;
    const int lane = tid & 63;

    // bijective XCD swizzle (nwg = 256)
    int flat = blockIdx.y * 2 + blockIdx.x;
    flat = (flat & 7) * 32 + (flat >> 3);
    const int bx = flat & 1;
    const int by = flat >> 1;
    const int m0 = by * 256;                 // global row (incl. batch)
    const int n0 = bx * 256;
    const int b  = m0 >> 12;                 // batch (256 | 4096)

    const int warp_m = wave >> 2;
    const int warp_n = wave & 3;
    const int fr = lane & 15;
    const int fq = lane >> 4;
    const int ch0 = ((fq ^ (fr & 7)) << 3);
    const int ch1 = ch0 ^ 32;

    const int r6 = tid >> 3;
    const int cs = (((tid & 7) ^ (r6 & 7)) << 3);
    const unsigned short* Asrc = qb + (size_t)(m0 + r6) * NDIM + cs;
    const unsigned short* Bsrc = M2b + (size_t)b * NDIM * NDIM
                               + (size_t)(n0 + (r6 >> 5) * 64 + (r6 & 31)) * NDIM + cs;
    const int sdst = wave * 512;

#define STG_A(tt, h, c) GLOAD_LDS16(Asrc + (size_t)((c) * 128 + (h) * 64) * NDIM + (tt) * 64, \
        &lds[(((tt) & 1) << 15) + ((h) << 13) + ((c) << 12) + sdst])
#define STG_B(tt, h, c) GLOAD_LDS16(Bsrc + (size_t)((c) * 128 + (h) * 32) * NDIM + (tt) * 64, \
        &lds[(((tt) & 1) << 15) + 16384 + ((h) << 13) + ((c) << 12) + sdst])
#define VMCNT4 asm volatile("s_waitcnt vmcnt(4)" ::: "memory")
#define BARF   { __builtin_amdgcn_s_barrier(); asm volatile("" ::: "memory"); }

    f32x4_t acc[8][4] = {};

    STG_A(0, 0, 0); STG_A(0, 0, 1);
    STG_B(0, 0, 0); STG_B(0, 0, 1);
    STG_B(0, 1, 0); STG_B(0, 1, 1);
    STG_A(0, 1, 0); STG_A(0, 1, 1);

    const unsigned short* Afr = &lds[(warp_m * 64 + fr) * 64];
    const unsigned short* Bfr = &lds[16384 + (warp_n * 32 + fr) * 64];

    bf16x8_t a0[4][2], a1[4][2], b0[2][2], b1[2][2];

    for (int tt = 0; tt < 7; ++tt) {
        const int rb = (tt & 1) << 15;
        VMCNT4; BARF;
        #pragma unroll
        for (int mi = 0; mi < 4; ++mi) {
            a0[mi][0] = *(const bf16x8_t*)&Afr[rb + mi * 1024 + ch0];
            a0[mi][1] = *(const bf16x8_t*)&Afr[rb + mi * 1024 + ch1];
        }
        #pragma unroll
        for (int nj = 0; nj < 2; ++nj) {
            b0[nj][0] = *(const bf16x8_t*)&Bfr[rb + nj * 1024 + ch0];
            b0[nj][1] = *(const bf16x8_t*)&Bfr[rb + nj * 1024 + ch1];
        }
        STG_A(tt + 1, 0, 0); STG_A(tt + 1, 0, 1);
        __builtin_amdgcn_s_setprio(1);
        #pragma unroll
        for (int mi = 0; mi < 4; ++mi)
            #pragma unroll
            for (int nj = 0; nj < 2; ++nj) {
                acc[mi][nj] = __builtin_amdgcn_mfma_f32_16x16x32_bf16(a0[mi][0], b0[nj][0], acc[mi][nj], 0, 0, 0);
                acc[mi][nj] = __builtin_amdgcn_mfma_f32_16x16x32_bf16(a0[mi][1], b0[nj][1], acc[mi][nj], 0, 0, 0);
            }
        __builtin_amdgcn_s_setprio(0);
        VMCNT4; BARF;
        #pragma unroll
        for (int nj = 0; nj < 2; ++nj) {
            b1[nj][0] = *(const bf16x8_t*)&Bfr[rb + 8192 + nj * 1024 + ch0];
            b1[nj][1] = *(const bf16x8_t*)&Bfr[rb + 8192 + nj * 1024 + ch1];
        }
        STG_B(tt + 1, 0, 0); STG_B(tt + 1, 0, 1);
        __builtin_amdgcn_s_setprio(1);
        #pragma unroll
        for (int mi = 0; mi < 4; ++mi)
            #pragma unroll
            for (int nj = 0; nj < 2; ++nj) {
                acc[mi][2 + nj] = __builtin_amdgcn_mfma_f32_16x16x32_bf16(a0[mi][0], b1[nj][0], acc[mi][2 + nj], 0, 0, 0);
                acc[mi][2 + nj] = __builtin_amdgcn_mfma_f32_16x16x32_bf16(a0[mi][1], b1[nj][1], acc[mi][2 + nj], 0, 0, 0);
            }
        __builtin_amdgcn_s_setprio(0);
        VMCNT4; BARF;
        #pragma unroll
        for (int mi = 0; mi < 4; ++mi) {
            a1[mi][0] = *(const bf16x8_t*)&Afr[rb + 8192 + mi * 1024 + ch0];
            a1[mi][1] = *(const bf16x8_t*)&Afr[rb + 8192 + mi * 1024 + ch1];
        }
        STG_B(tt + 1, 1, 0); STG_B(tt + 1, 1, 1);
        __builtin_amdgcn_s_setprio(1);
        #pragma unroll
        for (int mi = 0; mi < 4; ++mi)
            #pragma unroll
            for (int nj = 0; nj < 2; ++nj) {
                acc[4 + mi][nj] = __builtin_amdgcn_mfma_f32_16x16x32_bf16(a1[mi][0], b0[nj][0], acc[4 + mi][nj], 0, 0, 0);
                acc[4 + mi][nj] = __builtin_amdgcn_mfma_f32_16x16x32_bf16(a1[mi][1], b0[nj][1], acc[4 + mi][nj], 0, 0, 0);
            }
        __builtin_amdgcn_s_setprio(0);
        STG_A(tt + 1, 1, 0); STG_A(tt + 1, 1, 1);
        __builtin_amdgcn_s_setprio(1);
        #pragma unroll
        for (int mi = 0; mi < 4; ++mi)
            #pragma unroll
            for (int nj = 0; nj < 2; ++nj) {
                acc[4 + mi][2 + nj] = __builtin_amdgcn_mfma_f32_16x16x32_bf16(a1[mi][0], b1[nj][0], acc[4 + mi][2 + nj], 0, 0, 0);
                acc[4 + mi][2 + nj] = __builtin_amdgcn_mfma_f32_16x16x32_bf16(a1[mi][1], b1[nj][1], acc[4 + mi][2 + nj], 0, 0, 0);
            }
        __builtin_amdgcn_s_setprio(0);
    }
    {
        const int rb = 32768;
        asm volatile("s_waitcnt vmcnt(0)" ::: "memory");
        BARF;
        #pragma unroll
        for (int mi = 0; mi < 4; ++mi) {
            a0[mi][0] = *(const bf16x8_t*)&Afr[rb + mi * 1024 + ch0];
            a0[mi][1] = *(const bf16x8_t*)&Afr[rb + mi * 1024 + ch1];
        }
        #pragma unroll
        for (int nj = 0; nj < 2; ++nj) {
            b0[nj][0] = *(const bf16x8_t*)&Bfr[rb + nj * 1024 + ch0];
            b0[nj][1] = *(const bf16x8_t*)&Bfr[rb + nj * 1024 + ch1];
        }
        #pragma unroll
        for (int mi = 0; mi < 4; ++mi)
            #pragma unroll
            for (int nj = 0; nj < 2; ++nj) {
                acc[mi][nj] = __builtin_amdgcn_mfma_f32_16x16x32_bf16(a0[mi][0], b0[nj][0], acc[mi][nj], 0, 0, 0);
                acc[mi][nj] = __builtin_amdgcn_mfma_f32_16x16x32_bf16(a0[mi][1], b0[nj][1], acc[mi][nj], 0, 0, 0);
            }
        #pragma unroll
        for (int nj = 0; nj < 2; ++nj) {
            b1[nj][0] = *(const bf16x8_t*)&Bfr[rb + 8192 + nj * 1024 + ch0];
            b1[nj][1] = *(const bf16x8_t*)&Bfr[rb + 8192 + nj * 1024 + ch1];
        }
        #pragma unroll
        for (int mi = 0; mi < 4; ++mi)
            #pragma unroll
            for (int nj = 0; nj < 2; ++nj) {
                acc[mi][2 + nj] = __builtin_amdgcn_mfma_f32_16x16x32_bf16(a0[mi][0], b1[nj][0], acc[mi][2 + nj], 0, 0, 0);
                acc[mi][2 + nj] = __builtin_amdgcn_mfma_f32_16x16x32_bf16(a0[mi][1], b1[nj][1], acc[mi][2 + nj], 0, 0, 0);
            }
        #pragma unroll
        for (int mi = 0; mi < 4; ++mi) {
            a1[mi][0] = *(const bf16x8_t*)&Afr[rb + 8192 + mi * 1024 + ch0];
            a1[mi][1] = *(const bf16x8_t*)&Afr[rb + 8192 + mi * 1024 + ch1];
        }
        #pragma unroll
        for (int mi = 0; mi < 4; ++mi)
            #pragma unroll
            for (int nj = 0; nj < 2; ++nj) {
                acc[4 + mi][nj] = __builtin_amdgcn_mfma_f32_16x16x32_bf16(a1[mi][0], b0[nj][0], acc[4 + mi][nj], 0, 0, 0);
                acc[4 + mi][nj] = __builtin_amdgcn_mfma_f32_16x16x32_bf16(a1[mi][1], b0[nj][1], acc[4 + mi][nj], 0, 0, 0);
                acc[4 + mi][2 + nj] = __builtin_amdgcn_mfma_f32_16x16x32_bf16(a1[mi][0], b1[nj][0], acc[4 + mi][2 + nj], 0, 0, 0);
                acc[4 + mi][2 + nj] = __builtin_amdgcn_mfma_f32_16x16x32_bf16(a1[mi][1], b1[nj][1], acc[4 + mi][2 + nj], 0, 0, 0);
            }
    }
#undef STG_A
#undef STG_B
#undef VMCNT4
#undef BARF

    const int c  = lane & 15;
    const int g4 = (lane >> 4) * 4;
    const int mrow0 = m0 + warp_m * 128;
    const int ncol = n0 + warp_n * 64;

    #pragma unroll
    for (int j = 0; j < 4; ++j) {
        const int col = ncol + j * 16 + c;
        const float bb = bias[col];
        #pragma unroll
        for (int i = 0; i < 8; ++i) {
            const int row = mrow0 + (i >> 2) * 64 + (i & 3) * 16 + g4;
            float* cp = C + (size_t)row * NDIM + col;
            #pragma unroll
            for (int r = 0; r < 4; ++r)
                cp[(size_t)r * NDIM] = acc[i][j][r] + bb;
        }
    }
}

// ---------------------------------------------------------------------------
extern "C" void kernel_launch(void* const* d_in, const int* in_sizes, int n_in,
                              void* d_out, int out_size, void* d_ws, size_t ws_size,
                              hipStream_t stream)
{
    const float* x    = (const float*)d_in[0];
    const float* pos  = (const float*)d_in[1];
    const float* Wqkv = (const float*)d_in[2];
    const float* gk   = (const float*)d_in[3];
    const float* bk   = (const float*)d_in[4];
    const float* gv   = (const float*)d_in[5];
    const float* bv   = (const float*)d_in[6];
    const float* Wout = (const float*)d_in[7];
    const float* bout = (const float*)d_in[8];
    float* out = (float*)d_out;

    // ws: dots f32(1M) | M2b(4M) | qb(32M) | kT(32M) | vT(32M) | xb(32M)
    //     | Wqkvb(1.5M) | Woutb(.5M)
    float* dots = (float*)d_ws;
    unsigned short* M2b     = (unsigned short*)(dots + (size_t)NB * NH * 64 * 64);
    unsigned short* qb      = M2b + (size_t)NB * NDIM * NDIM;
    unsigned short* kT      = qb + (size_t)NROWS * NDIM;
    unsigned short* vT      = kT + (size_t)NB * NH * NDH * NN;
    unsigned short* xb      = vT + (size_t)NB * NH * NDH * NN;
    unsigned short* Wqkvb   = xb + (size_t)NROWS * NDIM;
    unsigned short* Woutb   = Wqkvb + (size_t)QKVC * NDIM;

    // 1) all fp32->bf16 converts + dots zeroing, one launch
    cvt_all<<<dim3(8768), dim3(256), 0, stream>>>(x, Wqkv, Wout, xb, Wqkvb, Woutb, dots);
    // 2) q -> qb, k/v -> kT/vT (transposed), LN+RoPE fused
    gemm_qkv_fused<<<dim3(QKVC / 256, NROWS / 256), dim3(512), 0, stream>>>(
        xb, Wqkvb, pos, gk, bk, gv, bv, qb, kT, vT);
    // 3) dots = k^T v per (b,h)  -- MFMA, fp32 atomics
    dots_mfma<<<dim3(NN / 512, NH, NB), dim3(256), 0, stream>>>(kT, vT, dots);
    // 4) M2b[b] = ((dots[b]/N) @ blockdiag) x Wout^T  (cvt fused in)
    dotsw_mfma<<<dim3(NDIM / 128, NH, NB), dim3(256), 0, stream>>>(Woutb, dots, M2b);
    // 5) out = q @ M2b[b]^T + bout  (256x256 4-phase, fp32 out)
    gemm_out_mfma256<<<dim3(2, NROWS / 256), dim3(512), 0, stream>>>(
        qb, M2b, bout, out);
}

// Round 5
// 266.319 us; speedup vs baseline: 1.2076x; 1.0439x over previous
//
#include <hip/hip_runtime.h>
#include <math.h>

#define NB 8
#define NN 4096
#define NDIM 512
#define NH 8
#define NDH 64
#define QKVC 1536
#define NROWS (NB * NN)
#define EPSF 1e-5f
#define INV_N (1.0f / 4096.0f)
// log2(10000)/16
#define L2_10K_16 0.8304820237218406f

typedef __bf16 bf16x8_t __attribute__((ext_vector_type(8)));
typedef float f32x4_t __attribute__((ext_vector_type(4)));
typedef unsigned short u16x8 __attribute__((ext_vector_type(8)));

__device__ inline unsigned short f2bf(float f) {
    unsigned u = __builtin_bit_cast(unsigned, f);
    u += 0x7fff + ((u >> 16) & 1);          // round-to-nearest-even
    return (unsigned short)(u >> 16);
}
__device__ inline float bf2f(unsigned short u) {
    unsigned v = (unsigned)u << 16;
    return __builtin_bit_cast(float, v);
}

// async global->LDS, 16B per lane; LDS dest = wave-uniform base + lane*16
#define GLOAD_LDS16(g, s) __builtin_amdgcn_global_load_lds(                    \
    (const __attribute__((address_space(1))) void*)(g),                        \
    (__attribute__((address_space(3))) void*)(s), 16, 0, 0)

// ---------------------------------------------------------------------------
// One kernel: fp32->bf16 for x / Wqkv / Wout, plus zeroing dots.
// ---------------------------------------------------------------------------
__device__ inline void cvt8v(const float* __restrict__ s,
                             unsigned short* __restrict__ d, int i)
{
    float4 a = *(const float4*)(s + i);
    float4 b = *(const float4*)(s + i + 4);
    ushort4 lo, hi;
    lo.x = f2bf(a.x); lo.y = f2bf(a.y); lo.z = f2bf(a.z); lo.w = f2bf(a.w);
    hi.x = f2bf(b.x); hi.y = f2bf(b.y); hi.z = f2bf(b.z); hi.w = f2bf(b.w);
    *(ushort4*)(d + i)     = lo;
    *(ushort4*)(d + i + 4) = hi;
}

__global__ __launch_bounds__(256)
void cvt_all(const float* __restrict__ x,  const float* __restrict__ wq,
             const float* __restrict__ wo,
             unsigned short* __restrict__ xb, unsigned short* __restrict__ wqb,
             unsigned short* __restrict__ wob, float* __restrict__ dots)
{
    const int bid = blockIdx.x, t = threadIdx.x;
    if (bid < 8192) {                       // x: 16.78M elems
        cvt8v(x, xb, (bid * 256 + t) * 8);
    } else if (bid < 8576) {                // Wqkv: 786432 elems
        cvt8v(wq, wqb, ((bid - 8192) * 256 + t) * 8);
    } else if (bid < 8704) {                // Wout: 262144 elems
        cvt8v(wo, wob, ((bid - 8576) * 256 + t) * 8);
    } else {                                // zero dots: 262144 floats
        const float4 z = {0.f, 0.f, 0.f, 0.f};
        float4* dp = (float4*)dots + (size_t)((bid - 8704) * 256 + t) * 4;
        dp[0] = z; dp[1] = z; dp[2] = z; dp[3] = z;
    }
}

// ---------------------------------------------------------------------------
// Fused QKV GEMM, 256x128 tile, BK=32, 8 waves (4M x 2N), per-wave C 64x64
// (one head). 48 KB double-buffered LDS + acc[4][4] (<=128 VGPR via
// launch_bounds(512,4)) -> 2 blocks/CU: one block's prologue/epilogue
// overlaps the other's K-loop (the R4 lesson: at 1 block/CU, ~23us/round of
// fill+drain+epilogue was fully exposed; K=512 is too short to amortize it).
// Counted vmcnt(3): stage tile t+1 while computing t; never drain mid-loop.
// Swizzle: 64B rows = 4 x 16B chunks; LDS[r][c] = G[r][c ^ ((r>>1)&3)]
// (2-way bank aliasing = free). Applied on global source (rule 21) + reads.
// Epilogue: RoPE(q,k) + LN(k,v); q -> qb row-major; k/v -> kT/vT transposed.
// ---------------------------------------------------------------------------
__global__ __launch_bounds__(512, 4)
void gemm_qkv_fused(const unsigned short* __restrict__ A,
                    const unsigned short* __restrict__ Bm,
                    const float* __restrict__ pos,
                    const float* __restrict__ gk, const float* __restrict__ bk,
                    const float* __restrict__ gv, const float* __restrict__ bvv,
                    unsigned short* __restrict__ qb,
                    unsigned short* __restrict__ kT,
                    unsigned short* __restrict__ vT)
{
    // shorts: A dbuf 2x8192 | B dbuf 2x4096 = 24576 shorts = 48 KB
    __shared__ __align__(16) unsigned short lds[24576];

    const int tid  = threadIdx.x;
    const int wave = tid >> 6;
    const int lane = tid & 63;

    // T1: bijective XCD swizzle (nwg = 1536, 1536 % 8 == 0)
    int flat = blockIdx.y * 12 + blockIdx.x;
    flat = (flat & 7) * 192 + (flat >> 3);
    const int bx = flat % 12;
    const int by = flat / 12;
    const int m0 = by * 256;
    const int n0 = bx * 128;

    const int warp_m = wave >> 1;       // 0..3 -> rows warp_m*64
    const int warp_n = wave & 1;        // 0..1 -> cols warp_n*64 (one head)
    const int fr = lane & 15;
    const int fq = lane >> 4;           // 0..3
    const int ch0 = ((fq ^ ((fr >> 1) & 3)) << 3);  // swizzled chunk (shorts)

    // stage source addressing (pre-swizzled global chunk, rule 21)
    const int rl = tid >> 2;                        // 0..127 row within call
    const int cs = (((tid & 3) ^ ((rl >> 1) & 3)) << 3);
    const unsigned short* Asrc = A  + (size_t)(m0 + rl) * NDIM + cs;
    const unsigned short* Bsrc = Bm + (size_t)(n0 + rl) * NDIM + cs;
    const int sdst = wave * 512;        // per-wave linear LDS dest (shorts)

#define STG_A(tt, c) GLOAD_LDS16(Asrc + (size_t)((c) * 128) * NDIM + (tt) * 32, \
        &lds[(((tt) & 1) * 8192) + ((c) * 4096) + sdst])
#define STG_B(tt)    GLOAD_LDS16(Bsrc + (tt) * 32, \
        &lds[16384 + (((tt) & 1) * 4096) + sdst])
#define VMCNT3 asm volatile("s_waitcnt vmcnt(3)" ::: "memory")
#define VMCNT0 asm volatile("s_waitcnt vmcnt(0)" ::: "memory")
#define BARF   { __builtin_amdgcn_s_barrier(); asm volatile("" ::: "memory"); }

    f32x4_t acc[4][4] = {};

    // prologue: stage tile 0 (3 loads)
    STG_A(0, 0); STG_A(0, 1); STG_B(0);

    #pragma unroll 2
    for (int tt = 0; tt < 16; ++tt) {
        BARF;                           // (1) all waves done reading tile tt-1
        if (tt < 15) { STG_A(tt + 1, 0); STG_A(tt + 1, 1); STG_B(tt + 1); VMCNT3; }
        else VMCNT0;
        BARF;                           // (2) all waves' tile-tt loads landed
        bf16x8_t af[4], bfr[4];
        const int ab = (tt & 1) * 8192;
        const int bb = 16384 + (tt & 1) * 4096;
        #pragma unroll
        for (int mi = 0; mi < 4; ++mi)
            af[mi] = *(const bf16x8_t*)&lds[ab + (warp_m * 64 + mi * 16 + fr) * 32 + ch0];
        #pragma unroll
        for (int nj = 0; nj < 4; ++nj)
            bfr[nj] = *(const bf16x8_t*)&lds[bb + (warp_n * 64 + nj * 16 + fr) * 32 + ch0];
        __builtin_amdgcn_s_setprio(1);
        #pragma unroll
        for (int mi = 0; mi < 4; ++mi)
            #pragma unroll
            for (int nj = 0; nj < 4; ++nj)
                acc[mi][nj] = __builtin_amdgcn_mfma_f32_16x16x32_bf16(
                    af[mi], bfr[nj], acc[mi][nj], 0, 0, 0);
        __builtin_amdgcn_s_setprio(0);
    }
#undef STG_A
#undef STG_B

    // ---- fused epilogue (wave owns 64 rows x 64 cols = one head's d-span) ----
    const int nc = n0 + warp_n * 64;            // global col base (uniform/wave)
    const int type = nc >> 9;                   // 0=q, 1=k, 2=v
    const int c  = lane & 15;
    const int g4 = (lane >> 4) * 4;
    const int mrow0 = m0 + warp_m * 64;

    if (type != 0) {                    // LN over head dim (k or v)
        const float* gamma = (type == 1) ? gk : gv;
        const float* beta  = (type == 1) ? bk : bvv;
        float gm[4], bt[4];
        #pragma unroll
        for (int j = 0; j < 4; ++j) { gm[j] = gamma[j * 16 + c]; bt[j] = beta[j * 16 + c]; }
        #pragma unroll
        for (int i = 0; i < 4; ++i)
            #pragma unroll
            for (int r = 0; r < 4; ++r) {
                float t0 = acc[i][0][r], t1 = acc[i][1][r];
                float t2 = acc[i][2][r], t3 = acc[i][3][r];
                float s  = t0 + t1 + t2 + t3;
                float ss = t0*t0 + t1*t1 + t2*t2 + t3*t3;
                #pragma unroll
                for (int msk = 1; msk < 16; msk <<= 1) {
                    s  += __shfl_xor(s,  msk, 64);
                    ss += __shfl_xor(ss, msk, 64);
                }
                const float mu = s * (1.0f / 64.0f);
                const float rs = rsqrtf(ss * (1.0f / 64.0f) - mu * mu + EPSF);
                acc[i][0][r] = (t0 - mu) * rs * gm[0] + bt[0];
                acc[i][1][r] = (t1 - mu) * rs * gm[1] + bt[1];
                acc[i][2][r] = (t2 - mu) * rs * gm[2] + bt[2];
                acc[i][3][r] = (t3 - mu) * rs * gm[3] + bt[3];
            }
    }
    if (type != 2) {                    // RoPE 2D (q or k)
        const float Kc = 64.0f * exp2f(-(float)c * L2_10K_16);
        #pragma unroll
        for (int i = 0; i < 4; ++i)
            #pragma unroll
            for (int r = 0; r < 4; ++r) {
                const int row = mrow0 + i * 16 + g4 + r;
                const float2 p = ((const float2*)pos)[row];
                float sx, cx, sy, cy;
                __sincosf(p.x * Kc, &sx, &cx);
                __sincosf(p.y * Kc, &sy, &cy);
                const float t0 = acc[i][0][r], t1 = acc[i][1][r];
                const float t2 = acc[i][2][r], t3 = acc[i][3][r];
                acc[i][0][r] = t0 * cx - t1 * sx;
                acc[i][1][r] = t1 * cx + t0 * sx;
                acc[i][2][r] = t2 * cy - t3 * sy;
                acc[i][3][r] = t3 * cy + t2 * sy;
            }
    }
    if (type == 0) {                    // q -> qb [m][512] row-major
        #pragma unroll
        for (int i = 0; i < 4; ++i)
            #pragma unroll
            for (int j = 0; j < 4; ++j) {
                unsigned short* qp = qb + (size_t)(mrow0 + i * 16 + g4) * NDIM
                                   + nc + j * 16 + c;
                #pragma unroll
                for (int r = 0; r < 4; ++r)
                    qp[(size_t)r * NDIM] = f2bf(acc[i][j][r]);
            }
    } else {                            // k/v -> kT/vT [b,h,d,n] (transposed)
        unsigned short* T = (type == 1) ? kT : vT;
        const int h = (nc >> 6) & 7;
        #pragma unroll
        for (int i = 0; i < 4; ++i) {
            const int row = mrow0 + i * 16 + g4;
            const int bb = row >> 12;           // batch
            const int nl = row & 4095;          // n within batch (4-aligned)
            #pragma unroll
            for (int j = 0; j < 4; ++j) {
                ushort4 o;
                o.x = f2bf(acc[i][j][0]); o.y = f2bf(acc[i][j][1]);
                o.z = f2bf(acc[i][j][2]); o.w = f2bf(acc[i][j][3]);
                *(ushort4*)(T + ((size_t)((bb * NH + h) * 64 + j * 16 + c)) * NN + nl) = o;
            }
        }
    }
}

// ---------------------------------------------------------------------------
// dots[b][h][d][e] = sum_n kT[b,h,d,n] * vT[b,h,e,n]  -- MFMA NT-GEMM.
// Grid (8 n-chunks, NH, NB), 256 thr (4 waves), per wave C 32x32 (2x2 frags).
// fp32 atomics out (8 blocks/tile).
// ---------------------------------------------------------------------------
__global__ __launch_bounds__(256)
void dots_mfma(const unsigned short* __restrict__ kT,
               const unsigned short* __restrict__ vT,
               float* __restrict__ dots)
{
    __shared__ __align__(16) unsigned short sk[2][64 * 64];
    __shared__ __align__(16) unsigned short sv[2][64 * 64];
    const int t = threadIdx.x;
    const int w = t >> 6, l = t & 63;
    const int bh = blockIdx.z * NH + blockIdx.y;
    const int n0 = blockIdx.x * 512;

    const int r8 = l >> 3;                     // 0..7
    const int cs = ((l & 7) ^ r8) * 8;         // swizzled source chunk (shorts)
    const unsigned short* ksrc = kT + (size_t)(bh * 64 + w * 16 + r8) * NN + n0 + cs;
    const unsigned short* vsrc = vT + (size_t)(bh * 64 + w * 16 + r8) * NN + n0 + cs;

    // wave w stages its 16 rows (2 calls of 8 rows) per operand per K-step
#define STGK(buf, kt, q) GLOAD_LDS16(ksrc + (size_t)(q) * 8 * NN + (kt), \
        &sk[buf][w * 1024 + (q) * 512])
#define STGV(buf, kt, q) GLOAD_LDS16(vsrc + (size_t)(q) * 8 * NN + (kt), \
        &sv[buf][w * 1024 + (q) * 512])

    const int fr = l & 15, fq = l >> 4;
    const int doff = (w >> 1) * 32, eoff = (w & 1) * 32;

    f32x4_t acc[2][2] = {};

    STGK(0, 0, 0); STGK(0, 0, 1); STGV(0, 0, 0); STGV(0, 0, 1);

    for (int s = 0; s < 8; ++s) {
        const int buf = s & 1;
        asm volatile("s_waitcnt vmcnt(0)" ::: "memory");
        __builtin_amdgcn_s_barrier();
        bf16x8_t ak[2][2], bv[2][2];
        #pragma unroll
        for (int di = 0; di < 2; ++di)
            #pragma unroll
            for (int ks = 0; ks < 2; ++ks)
                ak[di][ks] = *(const bf16x8_t*)
                    &sk[buf][(doff + di * 16 + fr) * 64 + (((ks * 4 + fq) ^ (fr & 7)) * 8)];
        #pragma unroll
        for (int ej = 0; ej < 2; ++ej)
            #pragma unroll
            for (int ks = 0; ks < 2; ++ks)
                bv[ej][ks] = *(const bf16x8_t*)
                    &sv[buf][(eoff + ej * 16 + fr) * 64 + (((ks * 4 + fq) ^ (fr & 7)) * 8)];
        if (s + 1 < 8) {
            const int nb = buf ^ 1, kt = (s + 1) * 64;
            STGK(nb, kt, 0); STGK(nb, kt, 1); STGV(nb, kt, 0); STGV(nb, kt, 1);
        }
        #pragma unroll
        for (int ks = 0; ks < 2; ++ks)
            #pragma unroll
            for (int di = 0; di < 2; ++di)
                #pragma unroll
                for (int ej = 0; ej < 2; ++ej)
                    acc[di][ej] = __builtin_amdgcn_mfma_f32_16x16x32_bf16(
                        ak[di][ks], bv[ej][ks], acc[di][ej], 0, 0, 0);
    }
#undef STGK
#undef STGV

    float* dp = dots + (size_t)bh * 64 * 64;
    const int cc = l & 15;
    const int rr = (l >> 4) * 4;
    #pragma unroll
    for (int di = 0; di < 2; ++di)
        #pragma unroll
        for (int ej = 0; ej < 2; ++ej)
            #pragma unroll
            for (int r = 0; r < 4; ++r)
                atomicAdd(dp + (doff + di * 16 + rr + r) * 64 + eoff + ej * 16 + cc,
                          acc[di][ej][r]);
}

// ---------------------------------------------------------------------------
// M2b[b][d'][h*64+d] = bf16( sum_e (dots[b,h,d,e]/N) * Woutb[d', h*64+e] )
// ---------------------------------------------------------------------------
__global__ __launch_bounds__(256)
void dotsw_mfma(const unsigned short* __restrict__ Woutb,
                const float* __restrict__ dots,
                unsigned short* __restrict__ M2b)
{
    __shared__ unsigned short As[128 * 64];   // Wout tile, row-major (16 KB)
    __shared__ unsigned short Bs[64 * 64];    // dots[b,h] bf16, row-major (8 KB)
    const int t = threadIdx.x;
    const int wave = t >> 6;
    const int lane = t & 63;
    const int dp0 = blockIdx.x * 128;
    const int h = blockIdx.y, b = blockIdx.z;

    const int srow = lane >> 3;               // 0..7
    const int scol = (lane & 7) * 8;
    const unsigned short* Ag = Woutb + (size_t)(dp0 + wave * 32 + srow) * NDIM
                             + h * NDH + scol;
    #pragma unroll
    for (int i = 0; i < 4; ++i)
        GLOAD_LDS16(Ag + (size_t)i * 8 * NDIM, As + wave * 2048 + i * 512);

    // B tile: read fp32 dots, scale by 1/N, convert to bf16 into Bs
    {
        const float* Dg = dots + (size_t)(b * NH + h) * 4096;
        const int dr = t >> 2;                // 0..63
        const int dc = (t & 3) * 16;          // 0,16,32,48
        const float* dgp = Dg + dr * 64 + dc;
        float4 f0 = *(const float4*)(dgp);
        float4 f1 = *(const float4*)(dgp + 4);
        float4 f2 = *(const float4*)(dgp + 8);
        float4 f3 = *(const float4*)(dgp + 12);
        ushort4 o0, o1, o2, o3;
        o0.x = f2bf(f0.x * INV_N); o0.y = f2bf(f0.y * INV_N);
        o0.z = f2bf(f0.z * INV_N); o0.w = f2bf(f0.w * INV_N);
        o1.x = f2bf(f1.x * INV_N); o1.y = f2bf(f1.y * INV_N);
        o1.z = f2bf(f1.z * INV_N); o1.w = f2bf(f1.w * INV_N);
        o2.x = f2bf(f2.x * INV_N); o2.y = f2bf(f2.y * INV_N);
        o2.z = f2bf(f2.z * INV_N); o2.w = f2bf(f2.w * INV_N);
        o3.x = f2bf(f3.x * INV_N); o3.y = f2bf(f3.y * INV_N);
        o3.z = f2bf(f3.z * INV_N); o3.w = f2bf(f3.w * INV_N);
        *(ushort4*)&Bs[dr * 64 + dc]      = o0;
        *(ushort4*)&Bs[dr * 64 + dc + 4]  = o1;
        *(ushort4*)&Bs[dr * 64 + dc + 8]  = o2;
        *(ushort4*)&Bs[dr * 64 + dc + 12] = o3;
    }
    __syncthreads();

    const int wm = (wave >> 1) * 64;          // d' quadrant
    const int wn = (wave & 1) * 32;           // d half
    const int fr = lane & 15;
    const int fq = (lane >> 4) * 8;

    f32x4_t acc[4][2] = {};
    #pragma unroll
    for (int kk = 0; kk < 2; ++kk) {
        bf16x8_t af[4], bf[2];
        #pragma unroll
        for (int i = 0; i < 4; ++i)
            af[i] = *(const bf16x8_t*)&As[(wm + i * 16 + fr) * 64 + kk * 32 + fq];
        #pragma unroll
        for (int j = 0; j < 2; ++j)
            bf[j] = *(const bf16x8_t*)&Bs[(wn + j * 16 + fr) * 64 + kk * 32 + fq];
        #pragma unroll
        for (int i = 0; i < 4; ++i)
            #pragma unroll
            for (int j = 0; j < 2; ++j)
                acc[i][j] = __builtin_amdgcn_mfma_f32_16x16x32_bf16(
                    af[i], bf[j], acc[i][j], 0, 0, 0);
    }

    const int c  = lane & 15;
    const int g4 = (lane >> 4) * 4;
    #pragma unroll
    for (int i = 0; i < 4; ++i)
        #pragma unroll
        for (int j = 0; j < 2; ++j) {
            unsigned short* mp = M2b + ((size_t)(b * NDIM) + dp0 + wm + i * 16 + g4) * NDIM
                               + h * NDH + wn + j * 16 + c;
            #pragma unroll
            for (int r = 0; r < 4; ++r)
                mp[(size_t)r * NDIM] = f2bf(acc[i][j][r]);
        }
}

// ---------------------------------------------------------------------------
// out[m][d'] = sum_hd q[m,hd] * M2b[b][d'][hd] + bout[d']   (fp32 out)
// 256x128 tile, BK=32 double-buffer (48 KB), 2 blocks/CU, counted vmcnt.
// Grid (4, 128) = 512 blocks. Same pipeline as gemm_qkv_fused.
// ---------------------------------------------------------------------------
__global__ __launch_bounds__(512, 4)
void gemm_out_mfma(const unsigned short* __restrict__ qb,
                   const unsigned short* __restrict__ M2b,
                   const float* __restrict__ bias, float* __restrict__ C)
{
    __shared__ __align__(16) unsigned short lds[24576];

    const int tid  = threadIdx.x;
    const int wave = tid >> 6;
    const int lane = tid & 63;

    // bijective XCD swizzle (nwg = 512)
    int flat = blockIdx.y * 4 + blockIdx.x;
    flat = (flat & 7) * 64 + (flat >> 3);
    const int bx = flat & 3;
    const int by = flat >> 2;
    const int m0 = by * 256;                 // global row (incl. batch)
    const int n0 = bx * 128;
    const int b  = m0 >> 12;                 // batch (256 | 4096)

    const int warp_m = wave >> 1;
    const int warp_n = wave & 1;
    const int fr = lane & 15;
    const int fq = lane >> 4;
    const int ch0 = ((fq ^ ((fr >> 1) & 3)) << 3);

    const int rl = tid >> 2;
    const int cs = (((tid & 3) ^ ((rl >> 1) & 3)) << 3);
    const unsigned short* Asrc = qb + (size_t)(m0 + rl) * NDIM + cs;
    const unsigned short* Bsrc = M2b + (size_t)b * NDIM * NDIM
                               + (size_t)(n0 + rl) * NDIM + cs;
    const int sdst = wave * 512;

#define STG_A(tt, c) GLOAD_LDS16(Asrc + (size_t)((c) * 128) * NDIM + (tt) * 32, \
        &lds[(((tt) & 1) * 8192) + ((c) * 4096) + sdst])
#define STG_B(tt)    GLOAD_LDS16(Bsrc + (tt) * 32, \
        &lds[16384 + (((tt) & 1) * 4096) + sdst])

    f32x4_t acc[4][4] = {};

    STG_A(0, 0); STG_A(0, 1); STG_B(0);

    #pragma unroll 2
    for (int tt = 0; tt < 16; ++tt) {
        BARF;
        if (tt < 15) { STG_A(tt + 1, 0); STG_A(tt + 1, 1); STG_B(tt + 1); VMCNT3; }
        else VMCNT0;
        BARF;
        bf16x8_t af[4], bfr[4];
        const int ab = (tt & 1) * 8192;
        const int bb = 16384 + (tt & 1) * 4096;
        #pragma unroll
        for (int mi = 0; mi < 4; ++mi)
            af[mi] = *(const bf16x8_t*)&lds[ab + (warp_m * 64 + mi * 16 + fr) * 32 + ch0];
        #pragma unroll
        for (int nj = 0; nj < 4; ++nj)
            bfr[nj] = *(const bf16x8_t*)&lds[bb + (warp_n * 64 + nj * 16 + fr) * 32 + ch0];
        __builtin_amdgcn_s_setprio(1);
        #pragma unroll
        for (int mi = 0; mi < 4; ++mi)
            #pragma unroll
            for (int nj = 0; nj < 4; ++nj)
                acc[mi][nj] = __builtin_amdgcn_mfma_f32_16x16x32_bf16(
                    af[mi], bfr[nj], acc[mi][nj], 0, 0, 0);
        __builtin_amdgcn_s_setprio(0);
    }
#undef STG_A
#undef STG_B

    const int c  = lane & 15;
    const int g4 = (lane >> 4) * 4;
    const int mrow0 = m0 + warp_m * 64;
    const int ncol = n0 + warp_n * 64;

    #pragma unroll
    for (int j = 0; j < 4; ++j) {
        const int col = ncol + j * 16 + c;
        const float bb = bias[col];
        #pragma unroll
        for (int i = 0; i < 4; ++i) {
            float* cp = C + (size_t)(mrow0 + i * 16 + g4) * NDIM + col;
            #pragma unroll
            for (int r = 0; r < 4; ++r)
                cp[(size_t)r * NDIM] = acc[i][j][r] + bb;
        }
    }
}

// ---------------------------------------------------------------------------
extern "C" void kernel_launch(void* const* d_in, const int* in_sizes, int n_in,
                              void* d_out, int out_size, void* d_ws, size_t ws_size,
                              hipStream_t stream)
{
    const float* x    = (const float*)d_in[0];
    const float* pos  = (const float*)d_in[1];
    const float* Wqkv = (const float*)d_in[2];
    const float* gk   = (const float*)d_in[3];
    const float* bk   = (const float*)d_in[4];
    const float* gv   = (const float*)d_in[5];
    const float* bv   = (const float*)d_in[6];
    const float* Wout = (const float*)d_in[7];
    const float* bout = (const float*)d_in[8];
    float* out = (float*)d_out;

    // ws: dots f32(1M) | M2b(4M) | qb(32M) | kT(32M) | vT(32M) | xb(32M)
    //     | Wqkvb(1.5M) | Woutb(.5M)
    float* dots = (float*)d_ws;
    unsigned short* M2b     = (unsigned short*)(dots + (size_t)NB * NH * 64 * 64);
    unsigned short* qb      = M2b + (size_t)NB * NDIM * NDIM;
    unsigned short* kT      = qb + (size_t)NROWS * NDIM;
    unsigned short* vT      = kT + (size_t)NB * NH * NDH * NN;
    unsigned short* xb      = vT + (size_t)NB * NH * NDH * NN;
    unsigned short* Wqkvb   = xb + (size_t)NROWS * NDIM;
    unsigned short* Woutb   = Wqkvb + (size_t)QKVC * NDIM;

    // 1) all fp32->bf16 converts + dots zeroing, one launch
    cvt_all<<<dim3(8768), dim3(256), 0, stream>>>(x, Wqkv, Wout, xb, Wqkvb, Woutb, dots);
    // 2) q -> qb, k/v -> kT/vT (transposed), LN+RoPE fused (2 blocks/CU)
    gemm_qkv_fused<<<dim3(QKVC / 128, NROWS / 256), dim3(512), 0, stream>>>(
        xb, Wqkvb, pos, gk, bk, gv, bv, qb, kT, vT);
    // 3) dots = k^T v per (b,h)  -- MFMA, fp32 atomics
    dots_mfma<<<dim3(NN / 512, NH, NB), dim3(256), 0, stream>>>(kT, vT, dots);
    // 4) M2b[b] = ((dots[b]/N) @ blockdiag) x Wout^T  (cvt fused in)
    dotsw_mfma<<<dim3(NDIM / 128, NH, NB), dim3(256), 0, stream>>>(Woutb, dots, M2b);
    // 5) out = q @ M2b[b]^T + bout  (256x128 BK=32, 2 blocks/CU, fp32 out)
    gemm_out_mfma<<<dim3(NDIM / 128, NROWS / 256), dim3(512), 0, stream>>>(
        qb, M2b, bout, out);
}

// Round 6
// 265.062 us; speedup vs baseline: 1.2133x; 1.0047x over previous
//
#include <hip/hip_runtime.h>
#include <math.h>

#define NB 8
#define NN 4096
#define NDIM 512
#define NH 8
#define NDH 64
#define QKVC 1536
#define NROWS (NB * NN)
#define EPSF 1e-5f
#define INV_N (1.0f / 4096.0f)
// log2(10000)/16
#define L2_10K_16 0.8304820237218406f

typedef __bf16 bf16x8_t __attribute__((ext_vector_type(8)));
typedef float f32x4_t __attribute__((ext_vector_type(4)));
typedef unsigned short u16x8 __attribute__((ext_vector_type(8)));

__device__ inline unsigned short f2bf(float f) {
    unsigned u = __builtin_bit_cast(unsigned, f);
    u += 0x7fff + ((u >> 16) & 1);          // round-to-nearest-even
    return (unsigned short)(u >> 16);
}
__device__ inline float bf2f(unsigned short u) {
    unsigned v = (unsigned)u << 16;
    return __builtin_bit_cast(float, v);
}

// async global->LDS, 16B per lane; LDS dest = wave-uniform base + lane*16
#define GLOAD_LDS16(g, s) __builtin_amdgcn_global_load_lds(                    \
    (const __attribute__((address_space(1))) void*)(g),                        \
    (__attribute__((address_space(3))) void*)(s), 16, 0, 0)

#define VMCNT3 asm volatile("s_waitcnt vmcnt(3)" ::: "memory")
#define VMCNT0 asm volatile("s_waitcnt vmcnt(0)" ::: "memory")
#define BARF   { __builtin_amdgcn_s_barrier(); asm volatile("" ::: "memory"); }

// ---------------------------------------------------------------------------
// One kernel: fp32->bf16 for x / Wqkv / Wout, plus zeroing dots.
// ---------------------------------------------------------------------------
__device__ inline void cvt8v(const float* __restrict__ s,
                             unsigned short* __restrict__ d, int i)
{
    float4 a = *(const float4*)(s + i);
    float4 b = *(const float4*)(s + i + 4);
    ushort4 lo, hi;
    lo.x = f2bf(a.x); lo.y = f2bf(a.y); lo.z = f2bf(a.z); lo.w = f2bf(a.w);
    hi.x = f2bf(b.x); hi.y = f2bf(b.y); hi.z = f2bf(b.z); hi.w = f2bf(b.w);
    *(ushort4*)(d + i)     = lo;
    *(ushort4*)(d + i + 4) = hi;
}

__global__ __launch_bounds__(256)
void cvt_all(const float* __restrict__ x,  const float* __restrict__ wq,
             const float* __restrict__ wo,
             unsigned short* __restrict__ xb, unsigned short* __restrict__ wqb,
             unsigned short* __restrict__ wob, float* __restrict__ dots)
{
    const int bid = blockIdx.x, t = threadIdx.x;
    if (bid < 8192) {                       // x: 16.78M elems
        cvt8v(x, xb, (bid * 256 + t) * 8);
    } else if (bid < 8576) {                // Wqkv: 786432 elems
        cvt8v(wq, wqb, ((bid - 8192) * 256 + t) * 8);
    } else if (bid < 8704) {                // Wout: 262144 elems
        cvt8v(wo, wob, ((bid - 8576) * 256 + t) * 8);
    } else {                                // zero dots: 262144 floats
        const float4 z = {0.f, 0.f, 0.f, 0.f};
        float4* dp = (float4*)dots + (size_t)((bid - 8704) * 256 + t) * 4;
        dp[0] = z; dp[1] = z; dp[2] = z; dp[3] = z;
    }
}

// ---------------------------------------------------------------------------
// K/V GEMM: cols 512..1535 of qkv. 256x128 tile, BK=32, dbuf 48 KB,
// 2 blocks/CU, counted vmcnt. Epilogue: LN(all) + RoPE(k only), stores
// transposed kT/vT [b,h,d,n]. Bm is pre-offset to Wqkv row 512.
// (Split from the fused qkv kernel for per-type timing; pipeline identical.)
// ---------------------------------------------------------------------------
__global__ __launch_bounds__(512, 4)
void gemm_kv_fused(const unsigned short* __restrict__ A,
                   const unsigned short* __restrict__ Bm,
                   const float* __restrict__ pos,
                   const float* __restrict__ gk, const float* __restrict__ bk,
                   const float* __restrict__ gv, const float* __restrict__ bvv,
                   unsigned short* __restrict__ kT,
                   unsigned short* __restrict__ vT)
{
    __shared__ __align__(16) unsigned short lds[24576];

    const int tid  = threadIdx.x;
    const int wave = tid >> 6;
    const int lane = tid & 63;

    // bijective XCD swizzle (nwg = 1024)
    int flat = blockIdx.y * 8 + blockIdx.x;
    flat = (flat & 7) * 128 + (flat >> 3);
    const int bx = flat & 7;
    const int by = flat >> 3;
    const int m0 = by * 256;
    const int n0 = bx * 128;            // 0..1023 within k|v span

    const int warp_m = wave >> 1;       // 0..3 -> rows warp_m*64
    const int warp_n = wave & 1;        // 0..1 -> cols warp_n*64 (one head)
    const int fr = lane & 15;
    const int fq = lane >> 4;           // 0..3
    const int ch0 = ((fq ^ ((fr >> 1) & 3)) << 3);  // swizzled chunk (shorts)

    const int rl = tid >> 2;                        // 0..127 row within call
    const int cs = (((tid & 3) ^ ((rl >> 1) & 3)) << 3);
    const unsigned short* Asrc = A  + (size_t)(m0 + rl) * NDIM + cs;
    const unsigned short* Bsrc = Bm + (size_t)(n0 + rl) * NDIM + cs;
    const int sdst = wave * 512;

#define STG_A(tt, c) GLOAD_LDS16(Asrc + (size_t)((c) * 128) * NDIM + (tt) * 32, \
        &lds[(((tt) & 1) * 8192) + ((c) * 4096) + sdst])
#define STG_B(tt)    GLOAD_LDS16(Bsrc + (tt) * 32, \
        &lds[16384 + (((tt) & 1) * 4096) + sdst])

    f32x4_t acc[4][4] = {};

    STG_A(0, 0); STG_A(0, 1); STG_B(0);

    #pragma unroll 2
    for (int tt = 0; tt < 16; ++tt) {
        BARF;
        if (tt < 15) { STG_A(tt + 1, 0); STG_A(tt + 1, 1); STG_B(tt + 1); VMCNT3; }
        else VMCNT0;
        BARF;
        bf16x8_t af[4], bfr[4];
        const int ab = (tt & 1) * 8192;
        const int bb = 16384 + (tt & 1) * 4096;
        #pragma unroll
        for (int mi = 0; mi < 4; ++mi)
            af[mi] = *(const bf16x8_t*)&lds[ab + (warp_m * 64 + mi * 16 + fr) * 32 + ch0];
        #pragma unroll
        for (int nj = 0; nj < 4; ++nj)
            bfr[nj] = *(const bf16x8_t*)&lds[bb + (warp_n * 64 + nj * 16 + fr) * 32 + ch0];
        __builtin_amdgcn_s_setprio(1);
        #pragma unroll
        for (int mi = 0; mi < 4; ++mi)
            #pragma unroll
            for (int nj = 0; nj < 4; ++nj)
                acc[mi][nj] = __builtin_amdgcn_mfma_f32_16x16x32_bf16(
                    af[mi], bfr[nj], acc[mi][nj], 0, 0, 0);
        __builtin_amdgcn_s_setprio(0);
    }
#undef STG_A
#undef STG_B

    // ---- epilogue: LN always; RoPE iff k; transposed store ----
    const int nc = n0 + warp_n * 64;            // 0..1023 (k: <512, v: >=512)
    const int isK = (nc < 512);
    const int c  = lane & 15;
    const int g4 = (lane >> 4) * 4;
    const int mrow0 = m0 + warp_m * 64;
    const int h = (nc >> 6) & 7;

    {                                   // LN over head dim
        const float* gamma = isK ? gk : gv;
        const float* beta  = isK ? bk : bvv;
        float gm[4], bt[4];
        #pragma unroll
        for (int j = 0; j < 4; ++j) { gm[j] = gamma[j * 16 + c]; bt[j] = beta[j * 16 + c]; }
        #pragma unroll
        for (int i = 0; i < 4; ++i)
            #pragma unroll
            for (int r = 0; r < 4; ++r) {
                float t0 = acc[i][0][r], t1 = acc[i][1][r];
                float t2 = acc[i][2][r], t3 = acc[i][3][r];
                float s  = t0 + t1 + t2 + t3;
                float ss = t0*t0 + t1*t1 + t2*t2 + t3*t3;
                #pragma unroll
                for (int msk = 1; msk < 16; msk <<= 1) {
                    s  += __shfl_xor(s,  msk, 64);
                    ss += __shfl_xor(ss, msk, 64);
                }
                const float mu = s * (1.0f / 64.0f);
                const float rs = rsqrtf(ss * (1.0f / 64.0f) - mu * mu + EPSF);
                acc[i][0][r] = (t0 - mu) * rs * gm[0] + bt[0];
                acc[i][1][r] = (t1 - mu) * rs * gm[1] + bt[1];
                acc[i][2][r] = (t2 - mu) * rs * gm[2] + bt[2];
                acc[i][3][r] = (t3 - mu) * rs * gm[3] + bt[3];
            }
    }
    if (isK) {                          // RoPE 2D (k only)
        const float Kc = 64.0f * exp2f(-(float)c * L2_10K_16);
        #pragma unroll
        for (int i = 0; i < 4; ++i)
            #pragma unroll
            for (int r = 0; r < 4; ++r) {
                const int row = mrow0 + i * 16 + g4 + r;
                const float2 p = ((const float2*)pos)[row];
                float sx, cx, sy, cy;
                __sincosf(p.x * Kc, &sx, &cx);
                __sincosf(p.y * Kc, &sy, &cy);
                const float t0 = acc[i][0][r], t1 = acc[i][1][r];
                const float t2 = acc[i][2][r], t3 = acc[i][3][r];
                acc[i][0][r] = t0 * cx - t1 * sx;
                acc[i][1][r] = t1 * cx + t0 * sx;
                acc[i][2][r] = t2 * cy - t3 * sy;
                acc[i][3][r] = t3 * cy + t2 * sy;
            }
    }
    unsigned short* T = isK ? kT : vT;
    #pragma unroll
    for (int i = 0; i < 4; ++i) {
        const int row = mrow0 + i * 16 + g4;
        const int bb = row >> 12;           // batch
        const int nl = row & 4095;          // n within batch (4-aligned)
        #pragma unroll
        for (int j = 0; j < 4; ++j) {
            ushort4 o;
            o.x = f2bf(acc[i][j][0]); o.y = f2bf(acc[i][j][1]);
            o.z = f2bf(acc[i][j][2]); o.w = f2bf(acc[i][j][3]);
            *(ushort4*)(T + ((size_t)((bb * NH + h) * 64 + j * 16 + c)) * NN + nl) = o;
        }
    }
}

// ---------------------------------------------------------------------------
// Q GEMM: cols 0..511 of qkv. Same pipeline. Epilogue: RoPE, row-major qb.
// ---------------------------------------------------------------------------
__global__ __launch_bounds__(512, 4)
void gemm_q_fused(const unsigned short* __restrict__ A,
                  const unsigned short* __restrict__ Bm,
                  const float* __restrict__ pos,
                  unsigned short* __restrict__ qb)
{
    __shared__ __align__(16) unsigned short lds[24576];

    const int tid  = threadIdx.x;
    const int wave = tid >> 6;
    const int lane = tid & 63;

    // bijective XCD swizzle (nwg = 512)
    int flat = blockIdx.y * 4 + blockIdx.x;
    flat = (flat & 7) * 64 + (flat >> 3);
    const int bx = flat & 3;
    const int by = flat >> 2;
    const int m0 = by * 256;
    const int n0 = bx * 128;

    const int warp_m = wave >> 1;
    const int warp_n = wave & 1;
    const int fr = lane & 15;
    const int fq = lane >> 4;
    const int ch0 = ((fq ^ ((fr >> 1) & 3)) << 3);

    const int rl = tid >> 2;
    const int cs = (((tid & 3) ^ ((rl >> 1) & 3)) << 3);
    const unsigned short* Asrc = A  + (size_t)(m0 + rl) * NDIM + cs;
    const unsigned short* Bsrc = Bm + (size_t)(n0 + rl) * NDIM + cs;
    const int sdst = wave * 512;

#define STG_A(tt, c) GLOAD_LDS16(Asrc + (size_t)((c) * 128) * NDIM + (tt) * 32, \
        &lds[(((tt) & 1) * 8192) + ((c) * 4096) + sdst])
#define STG_B(tt)    GLOAD_LDS16(Bsrc + (tt) * 32, \
        &lds[16384 + (((tt) & 1) * 4096) + sdst])

    f32x4_t acc[4][4] = {};

    STG_A(0, 0); STG_A(0, 1); STG_B(0);

    #pragma unroll 2
    for (int tt = 0; tt < 16; ++tt) {
        BARF;
        if (tt < 15) { STG_A(tt + 1, 0); STG_A(tt + 1, 1); STG_B(tt + 1); VMCNT3; }
        else VMCNT0;
        BARF;
        bf16x8_t af[4], bfr[4];
        const int ab = (tt & 1) * 8192;
        const int bb = 16384 + (tt & 1) * 4096;
        #pragma unroll
        for (int mi = 0; mi < 4; ++mi)
            af[mi] = *(const bf16x8_t*)&lds[ab + (warp_m * 64 + mi * 16 + fr) * 32 + ch0];
        #pragma unroll
        for (int nj = 0; nj < 4; ++nj)
            bfr[nj] = *(const bf16x8_t*)&lds[bb + (warp_n * 64 + nj * 16 + fr) * 32 + ch0];
        __builtin_amdgcn_s_setprio(1);
        #pragma unroll
        for (int mi = 0; mi < 4; ++mi)
            #pragma unroll
            for (int nj = 0; nj < 4; ++nj)
                acc[mi][nj] = __builtin_amdgcn_mfma_f32_16x16x32_bf16(
                    af[mi], bfr[nj], acc[mi][nj], 0, 0, 0);
        __builtin_amdgcn_s_setprio(0);
    }
#undef STG_A
#undef STG_B

    const int nc = n0 + warp_n * 64;
    const int c  = lane & 15;
    const int g4 = (lane >> 4) * 4;
    const int mrow0 = m0 + warp_m * 64;

    {                                   // RoPE 2D
        const float Kc = 64.0f * exp2f(-(float)c * L2_10K_16);
        #pragma unroll
        for (int i = 0; i < 4; ++i)
            #pragma unroll
            for (int r = 0; r < 4; ++r) {
                const int row = mrow0 + i * 16 + g4 + r;
                const float2 p = ((const float2*)pos)[row];
                float sx, cx, sy, cy;
                __sincosf(p.x * Kc, &sx, &cx);
                __sincosf(p.y * Kc, &sy, &cy);
                const float t0 = acc[i][0][r], t1 = acc[i][1][r];
                const float t2 = acc[i][2][r], t3 = acc[i][3][r];
                acc[i][0][r] = t0 * cx - t1 * sx;
                acc[i][1][r] = t1 * cx + t0 * sx;
                acc[i][2][r] = t2 * cy - t3 * sy;
                acc[i][3][r] = t3 * cy + t2 * sy;
            }
    }
    #pragma unroll
    for (int i = 0; i < 4; ++i)
        #pragma unroll
        for (int j = 0; j < 4; ++j) {
            unsigned short* qp = qb + (size_t)(mrow0 + i * 16 + g4) * NDIM
                               + nc + j * 16 + c;
            #pragma unroll
            for (int r = 0; r < 4; ++r)
                qp[(size_t)r * NDIM] = f2bf(acc[i][j][r]);
        }
}

// ---------------------------------------------------------------------------
// dots[b][h][d][e] = sum_n kT[b,h,d,n] * vT[b,h,e,n]  -- MFMA NT-GEMM.
// ---------------------------------------------------------------------------
__global__ __launch_bounds__(256)
void dots_mfma(const unsigned short* __restrict__ kT,
               const unsigned short* __restrict__ vT,
               float* __restrict__ dots)
{
    __shared__ __align__(16) unsigned short sk[2][64 * 64];
    __shared__ __align__(16) unsigned short sv[2][64 * 64];
    const int t = threadIdx.x;
    const int w = t >> 6, l = t & 63;
    const int bh = blockIdx.z * NH + blockIdx.y;
    const int n0 = blockIdx.x * 512;

    const int r8 = l >> 3;                     // 0..7
    const int cs = ((l & 7) ^ r8) * 8;         // swizzled source chunk (shorts)
    const unsigned short* ksrc = kT + (size_t)(bh * 64 + w * 16 + r8) * NN + n0 + cs;
    const unsigned short* vsrc = vT + (size_t)(bh * 64 + w * 16 + r8) * NN + n0 + cs;

#define STGK(buf, kt, q) GLOAD_LDS16(ksrc + (size_t)(q) * 8 * NN + (kt), \
        &sk[buf][w * 1024 + (q) * 512])
#define STGV(buf, kt, q) GLOAD_LDS16(vsrc + (size_t)(q) * 8 * NN + (kt), \
        &sv[buf][w * 1024 + (q) * 512])

    const int fr = l & 15, fq = l >> 4;
    const int doff = (w >> 1) * 32, eoff = (w & 1) * 32;

    f32x4_t acc[2][2] = {};

    STGK(0, 0, 0); STGK(0, 0, 1); STGV(0, 0, 0); STGV(0, 0, 1);

    for (int s = 0; s < 8; ++s) {
        const int buf = s & 1;
        asm volatile("s_waitcnt vmcnt(0)" ::: "memory");
        __builtin_amdgcn_s_barrier();
        bf16x8_t ak[2][2], bv[2][2];
        #pragma unroll
        for (int di = 0; di < 2; ++di)
            #pragma unroll
            for (int ks = 0; ks < 2; ++ks)
                ak[di][ks] = *(const bf16x8_t*)
                    &sk[buf][(doff + di * 16 + fr) * 64 + (((ks * 4 + fq) ^ (fr & 7)) * 8)];
        #pragma unroll
        for (int ej = 0; ej < 2; ++ej)
            #pragma unroll
            for (int ks = 0; ks < 2; ++ks)
                bv[ej][ks] = *(const bf16x8_t*)
                    &sv[buf][(eoff + ej * 16 + fr) * 64 + (((ks * 4 + fq) ^ (fr & 7)) * 8)];
        if (s + 1 < 8) {
            const int nb = buf ^ 1, kt = (s + 1) * 64;
            STGK(nb, kt, 0); STGK(nb, kt, 1); STGV(nb, kt, 0); STGV(nb, kt, 1);
        }
        #pragma unroll
        for (int ks = 0; ks < 2; ++ks)
            #pragma unroll
            for (int di = 0; di < 2; ++di)
                #pragma unroll
                for (int ej = 0; ej < 2; ++ej)
                    acc[di][ej] = __builtin_amdgcn_mfma_f32_16x16x32_bf16(
                        ak[di][ks], bv[ej][ks], acc[di][ej], 0, 0, 0);
    }
#undef STGK
#undef STGV

    float* dp = dots + (size_t)bh * 64 * 64;
    const int cc = l & 15;
    const int rr = (l >> 4) * 4;
    #pragma unroll
    for (int di = 0; di < 2; ++di)
        #pragma unroll
        for (int ej = 0; ej < 2; ++ej)
            #pragma unroll
            for (int r = 0; r < 4; ++r)
                atomicAdd(dp + (doff + di * 16 + rr + r) * 64 + eoff + ej * 16 + cc,
                          acc[di][ej][r]);
}

// ---------------------------------------------------------------------------
// M2b[b][d'][h*64+d] = bf16( sum_e (dots[b,h,d,e]/N) * Woutb[d', h*64+e] )
// ---------------------------------------------------------------------------
__global__ __launch_bounds__(256)
void dotsw_mfma(const unsigned short* __restrict__ Woutb,
                const float* __restrict__ dots,
                unsigned short* __restrict__ M2b)
{
    __shared__ unsigned short As[128 * 64];   // Wout tile, row-major (16 KB)
    __shared__ unsigned short Bs[64 * 64];    // dots[b,h] bf16, row-major (8 KB)
    const int t = threadIdx.x;
    const int wave = t >> 6;
    const int lane = t & 63;
    const int dp0 = blockIdx.x * 128;
    const int h = blockIdx.y, b = blockIdx.z;

    const int srow = lane >> 3;               // 0..7
    const int scol = (lane & 7) * 8;
    const unsigned short* Ag = Woutb + (size_t)(dp0 + wave * 32 + srow) * NDIM
                             + h * NDH + scol;
    #pragma unroll
    for (int i = 0; i < 4; ++i)
        GLOAD_LDS16(Ag + (size_t)i * 8 * NDIM, As + wave * 2048 + i * 512);

    // B tile: read fp32 dots, scale by 1/N, convert to bf16 into Bs
    {
        const float* Dg = dots + (size_t)(b * NH + h) * 4096;
        const int dr = t >> 2;                // 0..63
        const int dc = (t & 3) * 16;          // 0,16,32,48
        const float* dgp = Dg + dr * 64 + dc;
        float4 f0 = *(const float4*)(dgp);
        float4 f1 = *(const float4*)(dgp + 4);
        float4 f2 = *(const float4*)(dgp + 8);
        float4 f3 = *(const float4*)(dgp + 12);
        ushort4 o0, o1, o2, o3;
        o0.x = f2bf(f0.x * INV_N); o0.y = f2bf(f0.y * INV_N);
        o0.z = f2bf(f0.z * INV_N); o0.w = f2bf(f0.w * INV_N);
        o1.x = f2bf(f1.x * INV_N); o1.y = f2bf(f1.y * INV_N);
        o1.z = f2bf(f1.z * INV_N); o1.w = f2bf(f1.w * INV_N);
        o2.x = f2bf(f2.x * INV_N); o2.y = f2bf(f2.y * INV_N);
        o2.z = f2bf(f2.z * INV_N); o2.w = f2bf(f2.w * INV_N);
        o3.x = f2bf(f3.x * INV_N); o3.y = f2bf(f3.y * INV_N);
        o3.z = f2bf(f3.z * INV_N); o3.w = f2bf(f3.w * INV_N);
        *(ushort4*)&Bs[dr * 64 + dc]      = o0;
        *(ushort4*)&Bs[dr * 64 + dc + 4]  = o1;
        *(ushort4*)&Bs[dr * 64 + dc + 8]  = o2;
        *(ushort4*)&Bs[dr * 64 + dc + 12] = o3;
    }
    __syncthreads();

    const int wm = (wave >> 1) * 64;          // d' quadrant
    const int wn = (wave & 1) * 32;           // d half
    const int fr = lane & 15;
    const int fq = (lane >> 4) * 8;

    f32x4_t acc[4][2] = {};
    #pragma unroll
    for (int kk = 0; kk < 2; ++kk) {
        bf16x8_t af[4], bf[2];
        #pragma unroll
        for (int i = 0; i < 4; ++i)
            af[i] = *(const bf16x8_t*)&As[(wm + i * 16 + fr) * 64 + kk * 32 + fq];
        #pragma unroll
        for (int j = 0; j < 2; ++j)
            bf[j] = *(const bf16x8_t*)&Bs[(wn + j * 16 + fr) * 64 + kk * 32 + fq];
        #pragma unroll
        for (int i = 0; i < 4; ++i)
            #pragma unroll
            for (int j = 0; j < 2; ++j)
                acc[i][j] = __builtin_amdgcn_mfma_f32_16x16x32_bf16(
                    af[i], bf[j], acc[i][j], 0, 0, 0);
    }

    const int c  = lane & 15;
    const int g4 = (lane >> 4) * 4;
    #pragma unroll
    for (int i = 0; i < 4; ++i)
        #pragma unroll
        for (int j = 0; j < 2; ++j) {
            unsigned short* mp = M2b + ((size_t)(b * NDIM) + dp0 + wm + i * 16 + g4) * NDIM
                               + h * NDH + wn + j * 16 + c;
            #pragma unroll
            for (int r = 0; r < 4; ++r)
                mp[(size_t)r * NDIM] = f2bf(acc[i][j][r]);
        }
}

// ---------------------------------------------------------------------------
// out[m][d'] = sum_hd q[m,hd] * M2b[b][d'][hd] + bout[d']   (fp32 out)
// 256x128 tile, BK=32 double-buffer (48 KB), 2 blocks/CU, counted vmcnt.
// ---------------------------------------------------------------------------
__global__ __launch_bounds__(512, 4)
void gemm_out_mfma(const unsigned short* __restrict__ qb,
                   const unsigned short* __restrict__ M2b,
                   const float* __restrict__ bias, float* __restrict__ C)
{
    __shared__ __align__(16) unsigned short lds[24576];

    const int tid  = threadIdx.x;
    const int wave = tid >> 6;
    const int lane = tid & 63;

    // bijective XCD swizzle (nwg = 512)
    int flat = blockIdx.y * 4 + blockIdx.x;
    flat = (flat & 7) * 64 + (flat >> 3);
    const int bx = flat & 3;
    const int by = flat >> 2;
    const int m0 = by * 256;                 // global row (incl. batch)
    const int n0 = bx * 128;
    const int b  = m0 >> 12;                 // batch (256 | 4096)

    const int warp_m = wave >> 1;
    const int warp_n = wave & 1;
    const int fr = lane & 15;
    const int fq = lane >> 4;
    const int ch0 = ((fq ^ ((fr >> 1) & 3)) << 3);

    const int rl = tid >> 2;
    const int cs = (((tid & 3) ^ ((rl >> 1) & 3)) << 3);
    const unsigned short* Asrc = qb + (size_t)(m0 + rl) * NDIM + cs;
    const unsigned short* Bsrc = M2b + (size_t)b * NDIM * NDIM
                               + (size_t)(n0 + rl) * NDIM + cs;
    const int sdst = wave * 512;

#define STG_A(tt, c) GLOAD_LDS16(Asrc + (size_t)((c) * 128) * NDIM + (tt) * 32, \
        &lds[(((tt) & 1) * 8192) + ((c) * 4096) + sdst])
#define STG_B(tt)    GLOAD_LDS16(Bsrc + (tt) * 32, \
        &lds[16384 + (((tt) & 1) * 4096) + sdst])

    f32x4_t acc[4][4] = {};

    STG_A(0, 0); STG_A(0, 1); STG_B(0);

    #pragma unroll 2
    for (int tt = 0; tt < 16; ++tt) {
        BARF;
        if (tt < 15) { STG_A(tt + 1, 0); STG_A(tt + 1, 1); STG_B(tt + 1); VMCNT3; }
        else VMCNT0;
        BARF;
        bf16x8_t af[4], bfr[4];
        const int ab = (tt & 1) * 8192;
        const int bb = 16384 + (tt & 1) * 4096;
        #pragma unroll
        for (int mi = 0; mi < 4; ++mi)
            af[mi] = *(const bf16x8_t*)&lds[ab + (warp_m * 64 + mi * 16 + fr) * 32 + ch0];
        #pragma unroll
        for (int nj = 0; nj < 4; ++nj)
            bfr[nj] = *(const bf16x8_t*)&lds[bb + (warp_n * 64 + nj * 16 + fr) * 32 + ch0];
        __builtin_amdgcn_s_setprio(1);
        #pragma unroll
        for (int mi = 0; mi < 4; ++mi)
            #pragma unroll
            for (int nj = 0; nj < 4; ++nj)
                acc[mi][nj] = __builtin_amdgcn_mfma_f32_16x16x32_bf16(
                    af[mi], bfr[nj], acc[mi][nj], 0, 0, 0);
        __builtin_amdgcn_s_setprio(0);
    }
#undef STG_A
#undef STG_B

    const int c  = lane & 15;
    const int g4 = (lane >> 4) * 4;
    const int mrow0 = m0 + warp_m * 64;
    const int ncol = n0 + warp_n * 64;

    #pragma unroll
    for (int j = 0; j < 4; ++j) {
        const int col = ncol + j * 16 + c;
        const float bb = bias[col];
        #pragma unroll
        for (int i = 0; i < 4; ++i) {
            float* cp = C + (size_t)(mrow0 + i * 16 + g4) * NDIM + col;
            #pragma unroll
            for (int r = 0; r < 4; ++r)
                cp[(size_t)r * NDIM] = acc[i][j][r] + bb;
        }
    }
}

// ---------------------------------------------------------------------------
extern "C" void kernel_launch(void* const* d_in, const int* in_sizes, int n_in,
                              void* d_out, int out_size, void* d_ws, size_t ws_size,
                              hipStream_t stream)
{
    const float* x    = (const float*)d_in[0];
    const float* pos  = (const float*)d_in[1];
    const float* Wqkv = (const float*)d_in[2];
    const float* gk   = (const float*)d_in[3];
    const float* bk   = (const float*)d_in[4];
    const float* gv   = (const float*)d_in[5];
    const float* bv   = (const float*)d_in[6];
    const float* Wout = (const float*)d_in[7];
    const float* bout = (const float*)d_in[8];
    float* out = (float*)d_out;

    // ws: dots f32(1M) | M2b(4M) | qb(32M) | kT(32M) | vT(32M) | xb(32M)
    //     | Wqkvb(1.5M) | Woutb(.5M)
    float* dots = (float*)d_ws;
    unsigned short* M2b     = (unsigned short*)(dots + (size_t)NB * NH * 64 * 64);
    unsigned short* qb      = M2b + (size_t)NB * NDIM * NDIM;
    unsigned short* kT      = qb + (size_t)NROWS * NDIM;
    unsigned short* vT      = kT + (size_t)NB * NH * NDH * NN;
    unsigned short* xb      = vT + (size_t)NB * NH * NDH * NN;
    unsigned short* Wqkvb   = xb + (size_t)NROWS * NDIM;
    unsigned short* Woutb   = Wqkvb + (size_t)QKVC * NDIM;

    // 1) all fp32->bf16 converts + dots zeroing, one launch
    cvt_all<<<dim3(8768), dim3(256), 0, stream>>>(x, Wqkv, Wout, xb, Wqkvb, Woutb, dots);
    // 2a) k/v -> kT/vT (transposed), LN + RoPE(k) fused
    gemm_kv_fused<<<dim3(8, NROWS / 256), dim3(512), 0, stream>>>(
        xb, Wqkvb + (size_t)512 * NDIM, pos, gk, bk, gv, bv, kT, vT);
    // 2b) q -> qb row-major, RoPE fused
    gemm_q_fused<<<dim3(4, NROWS / 256), dim3(512), 0, stream>>>(
        xb, Wqkvb, pos, qb);
    // 3) dots = k^T v per (b,h)  -- MFMA, fp32 atomics
    dots_mfma<<<dim3(NN / 512, NH, NB), dim3(256), 0, stream>>>(kT, vT, dots);
    // 4) M2b[b] = ((dots[b]/N) @ blockdiag) x Wout^T  (cvt fused in)
    dotsw_mfma<<<dim3(NDIM / 128, NH, NB), dim3(256), 0, stream>>>(Woutb, dots, M2b);
    // 5) out = q @ M2b[b]^T + bout  (256x128 BK=32, 2 blocks/CU, fp32 out)
    gemm_out_mfma<<<dim3(NDIM / 128, NROWS / 256), dim3(512), 0, stream>>>(
        qb, M2b, bout, out);
}